// Round 3
// baseline (349.407 us; speedup 1.0000x reference)
//
#include <hip/hip_runtime.h>
#include <hip/hip_bf16.h>

// Problem constants (B,T,E,H,D) = (4,1024,1024,16,64)
#define BB 4
#define TT 1024
#define EE 1024
#define HH 16
#define DD 64
#define MM 4096    // B*T rows
#define NQKV 3072  // q|k|v packed cols
#define E4 4096    // 4*E

using short8  = __attribute__((ext_vector_type(8))) short;
using short4v = __attribute__((ext_vector_type(4))) short;
using f32x4   = __attribute__((ext_vector_type(4))) float;

__device__ __forceinline__ short f2bf(float f) {
    __hip_bfloat16 h = __float2bfloat16(f);
    return *reinterpret_cast<short*>(&h);
}

// async global->LDS, 16B per lane. LDS dest is wave-uniform base + lane*16.
__device__ __forceinline__ void gld16(const void* g, void* l) {
    __builtin_amdgcn_global_load_lds((__attribute__((address_space(1))) void*)g,
                                     (__attribute__((address_space(3))) void*)l,
                                     16, 0, 0);
}

// ---------------- transpose + convert: in fp32 [R][C] -> out bf16 [C][R] ----------------
__global__ __launch_bounds__(256) void tcvt_kernel(const float* __restrict__ in,
                                                   short* __restrict__ out,
                                                   int R, int C) {
    __shared__ short tile[64][65];
    const int c0 = blockIdx.x * 64, r0 = blockIdx.y * 64;
    const int tr = threadIdx.x >> 6;   // 0..3
    const int tc = threadIdx.x & 63;
#pragma unroll
    for (int i = 0; i < 16; ++i) {
        int r = i * 4 + tr;
        tile[tc][r] = f2bf(in[(size_t)(r0 + r) * C + c0 + tc]);
    }
    __syncthreads();
#pragma unroll
    for (int i = 0; i < 16; ++i) {
        int c = i * 4 + tr;
        out[(size_t)(c0 + c) * R + r0 + tc] = tile[c][tc];
    }
}

// pack Wq/Wk/Wv (H,E,D) -> bf16 W^T layout [3072][1024]: row = which*1024+head*64+d, col = e
__global__ __launch_bounds__(256) void pack_qkv_t(const float* __restrict__ Wq,
                                                  const float* __restrict__ Wk,
                                                  const float* __restrict__ Wv,
                                                  short* __restrict__ out) {
    __shared__ short tile[64][65];
    const int m = blockIdx.y;            // 0..47
    const int which = m >> 4, head = m & 15;
    const float* src = ((which == 0) ? Wq : (which == 1) ? Wk : Wv) + (size_t)head * EE * DD;
    const int e0 = blockIdx.x * 64;
    const int tr = threadIdx.x >> 6, tc = threadIdx.x & 63;
#pragma unroll
    for (int i = 0; i < 16; ++i) {
        int e = i * 4 + tr;
        tile[tc][e] = f2bf(src[(size_t)(e0 + e) * DD + tc]);   // tile[d][e_local]
    }
    __syncthreads();
#pragma unroll
    for (int i = 0; i < 16; ++i) {
        int d = i * 4 + tr;
        out[(size_t)(which * 1024 + head * 64 + d) * EE + e0 + tc] = tile[d][tc];
    }
}

// ---------------- V transpose: qkv V-part [b*T+t][2048 + c] -> vT[(b*1024+c)][t] ----------------
__global__ __launch_bounds__(256) void vtr_kernel(const short* __restrict__ qkv,
                                                  short* __restrict__ vT) {
    __shared__ short tile[64][68];
    const int b = blockIdx.z;
    const int t0 = blockIdx.x * 64, c0 = blockIdx.y * 64;
    const int tr = threadIdx.x >> 4;          // 0..15
    const int q4 = (threadIdx.x & 15) * 4;    // 0..60
#pragma unroll
    for (int i = 0; i < 4; ++i) {
        int t = i * 16 + tr;
        short4v v = *(const short4v*)&qkv[((size_t)b * TT + t0 + t) * NQKV + 2048 + c0 + q4];
        *(short4v*)&tile[t][q4] = v;
    }
    __syncthreads();
#pragma unroll
    for (int i = 0; i < 4; ++i) {
        int c = i * 16 + tr;
        short4v v;
        v[0] = tile[q4 + 0][c];
        v[1] = tile[q4 + 1][c];
        v[2] = tile[q4 + 2][c];
        v[3] = tile[q4 + 3][c];
        *(short4v*)&vT[((size_t)b * 1024 + c0 + c) * TT + t0 + q4] = v;
    }
}

// ---------------- LayerNorm (fp32 in -> bf16 out) ----------------
__global__ __launch_bounds__(256) void ln_kernel(const float* __restrict__ x,
                                                 const float* __restrict__ g,
                                                 const float* __restrict__ b,
                                                 short* __restrict__ out) {
    __shared__ float red[4];
    const int row = blockIdx.x;
    const int tid = threadIdx.x;
    float4 v = *(const float4*)&x[(size_t)row * EE + tid * 4];
    float s = v.x + v.y + v.z + v.w;
#pragma unroll
    for (int off = 32; off >= 1; off >>= 1) s += __shfl_xor(s, off, 64);
    if ((tid & 63) == 0) red[tid >> 6] = s;
    __syncthreads();
    float mean = (red[0] + red[1] + red[2] + red[3]) * (1.0f / EE);
    __syncthreads();
    float d0 = v.x - mean, d1 = v.y - mean, d2 = v.z - mean, d3 = v.w - mean;
    s = d0 * d0 + d1 * d1 + d2 * d2 + d3 * d3;
#pragma unroll
    for (int off = 32; off >= 1; off >>= 1) s += __shfl_xor(s, off, 64);
    if ((tid & 63) == 0) red[tid >> 6] = s;
    __syncthreads();
    float var = (red[0] + red[1] + red[2] + red[3]) * (1.0f / EE);
    float rstd = rsqrtf(var + 1e-5f);
    int c = tid * 4;
    short4v o;
    o[0] = f2bf(d0 * rstd * g[c + 0] + b[c + 0]);
    o[1] = f2bf(d1 * rstd * g[c + 1] + b[c + 1]);
    o[2] = f2bf(d2 * rstd * g[c + 2] + b[c + 2]);
    o[3] = f2bf(d3 * rstd * g[c + 3] + b[c + 3]);
    *(short4v*)&out[(size_t)row * EE + c] = o;
}

// ---------------- bf16 GEMM (m97 structure): C[M,N] = A[M,K] @ B[K,N] ----------------
template <int BN, bool HAS_BIAS, bool RELU, bool RESID, bool OUT_BF16>
__global__ __launch_bounds__(256) void gemm_bt(const short* __restrict__ A,
                                               const short* __restrict__ Bt,
                                               const float* __restrict__ bias,
                                               const float* __restrict__ resid,
                                               void* __restrict__ outp,
                                               int M, int N, int K) {
    constexpr int WRC = (BN == 128) ? 2 : 4;
    constexpr int WCC = (BN == 128) ? 2 : 1;
    constexpr int MI = 8 / WRC;
    constexpr int NI = BN / (16 * WCC);
    constexpr int BCH = BN / 32;

    __shared__ __align__(16) short As[128 * 64];
    __shared__ __align__(16) short Bs[BN * 64];

    const int tid = threadIdx.x;
    const int lane = tid & 63;
    const int wid = tid >> 6;
    const int wr = (WRC == 2) ? (wid >> 1) : wid;
    const int wc = (WCC == 2) ? (wid & 1) : 0;
    const int l15 = lane & 15, lhi = lane >> 4;
    const int row0 = blockIdx.y * 128, col0 = blockIdx.x * BN;

    const int srow = tid >> 3;
    const int scol = (tid & 7) * 8;

    const int wrow0 = wr * (16 * MI);
    const int wcol0 = wc * (16 * NI);

    f32x4 acc[MI][NI] = {};

    for (int k0 = 0; k0 < K; k0 += 64) {
        __syncthreads();
#pragma unroll
        for (int ch = 0; ch < 4; ++ch)
            gld16(&A[(size_t)(row0 + ch * 32 + srow) * K + k0 + scol],
                  &As[ch * 2048 + wid * 512]);
#pragma unroll
        for (int ch = 0; ch < BCH; ++ch)
            gld16(&Bt[(size_t)(col0 + ch * 32 + srow) * K + k0 + scol],
                  &Bs[ch * 2048 + wid * 512]);
        __syncthreads();
#pragma unroll
        for (int ks = 0; ks < 2; ++ks) {
            short8 af[MI], bf[NI];
#pragma unroll
            for (int mi = 0; mi < MI; ++mi)
                af[mi] = *(const short8*)&As[(wrow0 + mi * 16 + l15) * 64 + ks * 32 + lhi * 8];
#pragma unroll
            for (int ni = 0; ni < NI; ++ni)
                bf[ni] = *(const short8*)&Bs[(wcol0 + ni * 16 + l15) * 64 + ks * 32 + lhi * 8];
#pragma unroll
            for (int mi = 0; mi < MI; ++mi)
#pragma unroll
                for (int ni = 0; ni < NI; ++ni)
                    acc[mi][ni] = __builtin_amdgcn_mfma_f32_16x16x32_bf16(
                        af[mi], bf[ni], acc[mi][ni], 0, 0, 0);
        }
    }

    float* outf = (float*)outp;
    short* outb = (short*)outp;
#pragma unroll
    for (int mi = 0; mi < MI; ++mi)
#pragma unroll
        for (int ni = 0; ni < NI; ++ni)
#pragma unroll
            for (int r = 0; r < 4; ++r) {
                int row = row0 + wrow0 + mi * 16 + lhi * 4 + r;
                int col = col0 + wcol0 + ni * 16 + l15;
                float v = acc[mi][ni][r];
                if (HAS_BIAS) v += bias[col];
                if (RELU) v = fmaxf(v, 0.f);
                if (RESID) v += resid[(size_t)row * N + col];
                if (OUT_BF16) outb[(size_t)row * N + col] = f2bf(v);
                else outf[(size_t)row * N + col] = v;
            }
}

// ---------------- flash attention ----------------
// 1 wave per (b, h, 16 q-rows). KV tile = 64. K read from qkv (k-contiguous),
// V read from vT (kv-contiguous -> short8 vector loads). Online softmax.
__global__ __launch_bounds__(64) void attn_kernel(const short* __restrict__ qkv,
                                                  const short* __restrict__ vT,
                                                  short* __restrict__ obuf) {
    __shared__ short Pl[16][72];
    const int lane = threadIdx.x;
    const int l15 = lane & 15, lhi = lane >> 4;
    const int bid = blockIdx.x;
    const int b = bid >> 10;          // /(H * T/16)
    const int rem = bid & 1023;
    const int h = rem >> 6;
    const int q0 = (rem & 63) << 4;
    const size_t rbase = (size_t)b * TT;
    const int hq = h * 64;
    const short* vbase = vT + ((size_t)b * 1024 + hq) * TT;

    short8 aq[2];
#pragma unroll
    for (int ks = 0; ks < 2; ++ks)
        aq[ks] = *(const short8*)&qkv[(rbase + q0 + l15) * NQKV + hq + ks * 32 + lhi * 8];

    float mrun[4], lsum[4];
    f32x4 o[4] = {};
#pragma unroll
    for (int r = 0; r < 4; ++r) { mrun[r] = -INFINITY; lsum[r] = 0.f; }

    for (int st = 0; st < TT; st += 64) {
        // V fragments: issue early so L2 latency hides under softmax VALU work
        short8 vf[4][2];
#pragma unroll
        for (int dt = 0; dt < 4; ++dt)
#pragma unroll
            for (int k2 = 0; k2 < 2; ++k2)
                vf[dt][k2] = *(const short8*)&vbase[(size_t)(dt * 16 + l15) * TT +
                                                   st + k2 * 32 + lhi * 8];
        f32x4 s[4] = {};
#pragma unroll
        for (int nt = 0; nt < 4; ++nt)
#pragma unroll
            for (int ks = 0; ks < 2; ++ks) {
                short8 kf = *(const short8*)&qkv[(rbase + st + nt * 16 + l15) * NQKV +
                                                 1024 + hq + ks * 32 + lhi * 8];
                s[nt] = __builtin_amdgcn_mfma_f32_16x16x32_bf16(aq[ks], kf, s[nt], 0, 0, 0);
            }
        float fac[4], p[4][4];
#pragma unroll
        for (int r = 0; r < 4; ++r) {
            float tmax = fmaxf(fmaxf(s[0][r], s[1][r]), fmaxf(s[2][r], s[3][r]));
#pragma unroll
            for (int off = 1; off < 16; off <<= 1)
                tmax = fmaxf(tmax, __shfl_xor(tmax, off, 16));
            float mnew = fmaxf(mrun[r], tmax);
            fac[r] = __expf(mrun[r] - mnew);
            float rs = 0.f;
#pragma unroll
            for (int nt = 0; nt < 4; ++nt) {
                p[nt][r] = __expf(s[nt][r] - mnew);
                rs += p[nt][r];
            }
#pragma unroll
            for (int off = 1; off < 16; off <<= 1) rs += __shfl_xor(rs, off, 16);
            lsum[r] = lsum[r] * fac[r] + rs;
            mrun[r] = mnew;
        }
#pragma unroll
        for (int dt = 0; dt < 4; ++dt)
#pragma unroll
            for (int r = 0; r < 4; ++r) o[dt][r] *= fac[r];

        __syncthreads();
#pragma unroll
        for (int nt = 0; nt < 4; ++nt)
#pragma unroll
            for (int r = 0; r < 4; ++r)
                Pl[lhi * 4 + r][nt * 16 + l15] = f2bf(p[nt][r]);
        __syncthreads();
        short8 pa[2];
        pa[0] = *(const short8*)&Pl[l15][lhi * 8];
        pa[1] = *(const short8*)&Pl[l15][32 + lhi * 8];
#pragma unroll
        for (int dt = 0; dt < 4; ++dt)
#pragma unroll
            for (int k2 = 0; k2 < 2; ++k2)
                o[dt] = __builtin_amdgcn_mfma_f32_16x16x32_bf16(pa[k2], vf[dt][k2],
                                                                o[dt], 0, 0, 0);
    }
#pragma unroll
    for (int r = 0; r < 4; ++r) lsum[r] = 1.0f / lsum[r];
#pragma unroll
    for (int dt = 0; dt < 4; ++dt)
#pragma unroll
        for (int r = 0; r < 4; ++r)
            obuf[(rbase + q0 + lhi * 4 + r) * EE + hq + dt * 16 + l15] =
                f2bf(o[dt][r] * lsum[r]);
}

// ---------------- launch ----------------
extern "C" void kernel_launch(void* const* d_in, const int* in_sizes, int n_in,
                              void* d_out, int out_size, void* d_ws, size_t ws_size,
                              hipStream_t stream) {
    const float* x   = (const float*)d_in[0];
    const float* g1  = (const float*)d_in[1];
    const float* be1 = (const float*)d_in[2];
    const float* Wq  = (const float*)d_in[3];
    const float* Wk  = (const float*)d_in[4];
    const float* Wv  = (const float*)d_in[5];
    const float* Wp  = (const float*)d_in[6];
    const float* bp  = (const float*)d_in[7];
    const float* g2  = (const float*)d_in[8];
    const float* be2 = (const float*)d_in[9];
    const float* W1  = (const float*)d_in[10];
    const float* b1f = (const float*)d_in[11];
    const float* W2  = (const float*)d_in[12];
    const float* b2f = (const float*)d_in[13];

    char* p = (char*)d_ws;
    short* h_bf   = (short*)p; p += (size_t)MM * EE * 2;
    short* wqkv   = (short*)p; p += (size_t)EE * NQKV * 2;   // [3072][1024] W^T
    short* qkv    = (short*)p; p += (size_t)MM * NQKV * 2;
    short* o_bf   = (short*)p; p += (size_t)MM * EE * 2;
    short* wp_bf  = (short*)p; p += (size_t)EE * EE * 2;     // [1024][1024] Wp^T
    float* x1     = (float*)p; p += (size_t)MM * EE * 4;
    short* h2_bf  = (short*)p; p += (size_t)MM * EE * 2;
    short* w1_bf  = (short*)p; p += (size_t)EE * E4 * 2;     // [4096][1024] W1^T
    short* mid_bf = (short*)p; p += (size_t)MM * E4 * 2;
    short* w2_bf  = (short*)p; p += (size_t)E4 * EE * 2;     // [1024][4096] W2^T
    short* vTb    = (short*)p; p += (size_t)BB * 1024 * TT * 2;  // [b][h*64+d][t]

    pack_qkv_t<<<dim3(16, 48), 256, 0, stream>>>(Wq, Wk, Wv, wqkv);
    tcvt_kernel<<<dim3(16, 16), 256, 0, stream>>>(Wp, wp_bf, EE, EE);
    tcvt_kernel<<<dim3(64, 16), 256, 0, stream>>>(W1, w1_bf, EE, E4);
    tcvt_kernel<<<dim3(16, 64), 256, 0, stream>>>(W2, w2_bf, E4, EE);

    ln_kernel<<<MM, 256, 0, stream>>>(x, g1, be1, h_bf);

    gemm_bt<128, false, false, false, true>
        <<<dim3(NQKV / 128, MM / 128), 256, 0, stream>>>(h_bf, wqkv, nullptr, nullptr,
                                                         qkv, MM, NQKV, EE);

    vtr_kernel<<<dim3(16, 16, BB), 256, 0, stream>>>(qkv, vTb);

    attn_kernel<<<BB * HH * (TT / 16), 64, 0, stream>>>(qkv, vTb, o_bf);

    gemm_bt<64, true, false, true, false>
        <<<dim3(EE / 64, MM / 128), 256, 0, stream>>>(o_bf, wp_bf, bp, x, x1, MM, EE, EE);

    ln_kernel<<<MM, 256, 0, stream>>>(x1, g2, be2, h2_bf);

    gemm_bt<128, true, true, false, true>
        <<<dim3(E4 / 128, MM / 128), 256, 0, stream>>>(h2_bf, w1_bf, b1f, nullptr,
                                                       mid_bf, MM, E4, EE);

    gemm_bt<64, true, false, true, false>
        <<<dim3(EE / 64, MM / 128), 256, 0, stream>>>(mid_bf, w2_bf, b2f, x1,
                                                      (float*)d_out, MM, EE, E4);
}

// Round 4
// 303.693 us; speedup vs baseline: 1.1505x; 1.1505x over previous
//
#include <hip/hip_runtime.h>
#include <hip/hip_bf16.h>

// Problem constants (B,T,E,H,D) = (4,1024,1024,16,64)
#define BB 4
#define TT 1024
#define EE 1024
#define HH 16
#define DD 64
#define MM 4096    // B*T rows
#define NQKV 3072  // q|k|v packed cols
#define E4 4096    // 4*E

using short8  = __attribute__((ext_vector_type(8))) short;
using short4v = __attribute__((ext_vector_type(4))) short;
using f32x4   = __attribute__((ext_vector_type(4))) float;

__device__ __forceinline__ short f2bf(float f) {
    __hip_bfloat16 h = __float2bfloat16(f);
    return *reinterpret_cast<short*>(&h);
}

// async global->LDS, 16B per lane. LDS dest is wave-uniform base + lane*16.
__device__ __forceinline__ void gld16(const void* g, void* l) {
    __builtin_amdgcn_global_load_lds((__attribute__((address_space(1))) void*)g,
                                     (__attribute__((address_space(3))) void*)l,
                                     16, 0, 0);
}

// ---------------- transpose + convert: in fp32 [R][C] -> out bf16 [C][R] ----------------
__global__ __launch_bounds__(256) void tcvt_kernel(const float* __restrict__ in,
                                                   short* __restrict__ out,
                                                   int R, int C) {
    __shared__ short tile[64][65];
    const int c0 = blockIdx.x * 64, r0 = blockIdx.y * 64;
    const int tr = threadIdx.x >> 6;   // 0..3
    const int tc = threadIdx.x & 63;
#pragma unroll
    for (int i = 0; i < 16; ++i) {
        int r = i * 4 + tr;
        tile[tc][r] = f2bf(in[(size_t)(r0 + r) * C + c0 + tc]);
    }
    __syncthreads();
#pragma unroll
    for (int i = 0; i < 16; ++i) {
        int c = i * 4 + tr;
        out[(size_t)(c0 + c) * R + r0 + tc] = tile[c][tc];
    }
}

// pack Wq/Wk/Wv (H,E,D) -> bf16 W^T layout [3072][1024]: row = which*1024+head*64+d, col = e
__global__ __launch_bounds__(256) void pack_qkv_t(const float* __restrict__ Wq,
                                                  const float* __restrict__ Wk,
                                                  const float* __restrict__ Wv,
                                                  short* __restrict__ out) {
    __shared__ short tile[64][65];
    const int m = blockIdx.y;            // 0..47
    const int which = m >> 4, head = m & 15;
    const float* src = ((which == 0) ? Wq : (which == 1) ? Wk : Wv) + (size_t)head * EE * DD;
    const int e0 = blockIdx.x * 64;
    const int tr = threadIdx.x >> 6, tc = threadIdx.x & 63;
#pragma unroll
    for (int i = 0; i < 16; ++i) {
        int e = i * 4 + tr;
        tile[tc][e] = f2bf(src[(size_t)(e0 + e) * DD + tc]);   // tile[d][e_local]
    }
    __syncthreads();
#pragma unroll
    for (int i = 0; i < 16; ++i) {
        int d = i * 4 + tr;
        out[(size_t)(which * 1024 + head * 64 + d) * EE + e0 + tc] = tile[d][tc];
    }
}

// ---------------- V transpose: qkv V-part [b*T+t][2048 + c] -> vT[(b*1024+c)][t] ----------------
__global__ __launch_bounds__(256) void vtr_kernel(const short* __restrict__ qkv,
                                                  short* __restrict__ vT) {
    __shared__ short tile[64][68];
    const int b = blockIdx.z;
    const int t0 = blockIdx.x * 64, c0 = blockIdx.y * 64;
    const int tr = threadIdx.x >> 4;          // 0..15
    const int q4 = (threadIdx.x & 15) * 4;    // 0..60
#pragma unroll
    for (int i = 0; i < 4; ++i) {
        int t = i * 16 + tr;
        short4v v = *(const short4v*)&qkv[((size_t)b * TT + t0 + t) * NQKV + 2048 + c0 + q4];
        *(short4v*)&tile[t][q4] = v;
    }
    __syncthreads();
#pragma unroll
    for (int i = 0; i < 4; ++i) {
        int c = i * 16 + tr;
        short4v v;
        v[0] = tile[q4 + 0][c];
        v[1] = tile[q4 + 1][c];
        v[2] = tile[q4 + 2][c];
        v[3] = tile[q4 + 3][c];
        *(short4v*)&vT[((size_t)b * 1024 + c0 + c) * TT + t0 + q4] = v;
    }
}

// ---------------- LayerNorm (fp32 in -> bf16 out) ----------------
__global__ __launch_bounds__(256) void ln_kernel(const float* __restrict__ x,
                                                 const float* __restrict__ g,
                                                 const float* __restrict__ b,
                                                 short* __restrict__ out) {
    __shared__ float red[4];
    const int row = blockIdx.x;
    const int tid = threadIdx.x;
    float4 v = *(const float4*)&x[(size_t)row * EE + tid * 4];
    float s = v.x + v.y + v.z + v.w;
#pragma unroll
    for (int off = 32; off >= 1; off >>= 1) s += __shfl_xor(s, off, 64);
    if ((tid & 63) == 0) red[tid >> 6] = s;
    __syncthreads();
    float mean = (red[0] + red[1] + red[2] + red[3]) * (1.0f / EE);
    __syncthreads();
    float d0 = v.x - mean, d1 = v.y - mean, d2 = v.z - mean, d3 = v.w - mean;
    s = d0 * d0 + d1 * d1 + d2 * d2 + d3 * d3;
#pragma unroll
    for (int off = 32; off >= 1; off >>= 1) s += __shfl_xor(s, off, 64);
    if ((tid & 63) == 0) red[tid >> 6] = s;
    __syncthreads();
    float var = (red[0] + red[1] + red[2] + red[3]) * (1.0f / EE);
    float rstd = rsqrtf(var + 1e-5f);
    int c = tid * 4;
    short4v o;
    o[0] = f2bf(d0 * rstd * g[c + 0] + b[c + 0]);
    o[1] = f2bf(d1 * rstd * g[c + 1] + b[c + 1]);
    o[2] = f2bf(d2 * rstd * g[c + 2] + b[c + 2]);
    o[3] = f2bf(d3 * rstd * g[c + 3] + b[c + 3]);
    *(short4v*)&out[(size_t)row * EE + c] = o;
}

// ---------------- bf16 GEMM (m97 structure): C[M,N] = A[M,K] @ B[K,N] ----------------
template <int BN, bool HAS_BIAS, bool RELU, bool RESID, bool OUT_BF16>
__global__ __launch_bounds__(256) void gemm_bt(const short* __restrict__ A,
                                               const short* __restrict__ Bt,
                                               const float* __restrict__ bias,
                                               const float* __restrict__ resid,
                                               void* __restrict__ outp,
                                               int M, int N, int K) {
    constexpr int WRC = (BN == 128) ? 2 : 4;
    constexpr int WCC = (BN == 128) ? 2 : 1;
    constexpr int MI = 8 / WRC;
    constexpr int NI = BN / (16 * WCC);
    constexpr int BCH = BN / 32;

    __shared__ __align__(16) short As[128 * 64];
    __shared__ __align__(16) short Bs[BN * 64];

    const int tid = threadIdx.x;
    const int lane = tid & 63;
    const int wid = tid >> 6;
    const int wr = (WRC == 2) ? (wid >> 1) : wid;
    const int wc = (WCC == 2) ? (wid & 1) : 0;
    const int l15 = lane & 15, lhi = lane >> 4;
    const int row0 = blockIdx.y * 128, col0 = blockIdx.x * BN;

    const int srow = tid >> 3;
    const int scol = (tid & 7) * 8;

    const int wrow0 = wr * (16 * MI);
    const int wcol0 = wc * (16 * NI);

    f32x4 acc[MI][NI] = {};

    for (int k0 = 0; k0 < K; k0 += 64) {
        __syncthreads();
#pragma unroll
        for (int ch = 0; ch < 4; ++ch)
            gld16(&A[(size_t)(row0 + ch * 32 + srow) * K + k0 + scol],
                  &As[ch * 2048 + wid * 512]);
#pragma unroll
        for (int ch = 0; ch < BCH; ++ch)
            gld16(&Bt[(size_t)(col0 + ch * 32 + srow) * K + k0 + scol],
                  &Bs[ch * 2048 + wid * 512]);
        __syncthreads();
#pragma unroll
        for (int ks = 0; ks < 2; ++ks) {
            short8 af[MI], bf[NI];
#pragma unroll
            for (int mi = 0; mi < MI; ++mi)
                af[mi] = *(const short8*)&As[(wrow0 + mi * 16 + l15) * 64 + ks * 32 + lhi * 8];
#pragma unroll
            for (int ni = 0; ni < NI; ++ni)
                bf[ni] = *(const short8*)&Bs[(wcol0 + ni * 16 + l15) * 64 + ks * 32 + lhi * 8];
#pragma unroll
            for (int mi = 0; mi < MI; ++mi)
#pragma unroll
                for (int ni = 0; ni < NI; ++ni)
                    acc[mi][ni] = __builtin_amdgcn_mfma_f32_16x16x32_bf16(
                        af[mi], bf[ni], acc[mi][ni], 0, 0, 0);
        }
    }

    float* outf = (float*)outp;
    short* outb = (short*)outp;
#pragma unroll
    for (int mi = 0; mi < MI; ++mi)
#pragma unroll
        for (int ni = 0; ni < NI; ++ni)
#pragma unroll
            for (int r = 0; r < 4; ++r) {
                int row = row0 + wrow0 + mi * 16 + lhi * 4 + r;
                int col = col0 + wcol0 + ni * 16 + l15;
                float v = acc[mi][ni][r];
                if (HAS_BIAS) v += bias[col];
                if (RELU) v = fmaxf(v, 0.f);
                if (RESID) v += resid[(size_t)row * N + col];
                if (OUT_BF16) outb[(size_t)row * N + col] = f2bf(v);
                else outf[(size_t)row * N + col] = v;
            }
}

// ---------------- flash attention (4-wave block, LDS-staged K/V) ----------------
// Block = 4 waves, 64 q-rows (wave w owns rows q0+16w..+16). KVBLK=64.
// K staged [64 kv][64 d] from qkv; V staged [64 d][64 kv] from vT. Both via
// global_load_lds(16). Fragments via ds_read_b128. Online softmax per wave.
__global__ __launch_bounds__(256) void attn_kernel(const short* __restrict__ qkv,
                                                   const short* __restrict__ vT,
                                                   short* __restrict__ obuf) {
    __shared__ __align__(16) short Ks[64 * 64];   // [kv][d]
    __shared__ __align__(16) short Vs[64 * 64];   // [d][kv]
    __shared__ short Pl[4][16][72];
    const int tid = threadIdx.x;
    const int lane = tid & 63;
    const int wid = tid >> 6;
    const int l15 = lane & 15, lhi = lane >> 4;
    const int bid = blockIdx.x;
    const int b = bid >> 8;
    const int h = (bid >> 4) & 15;
    const int q0 = (bid & 15) * 64;
    const size_t rbase = (size_t)b * TT;
    const int hq = h * 64;
    const short* vg = vT + ((size_t)b * 1024 + hq) * TT;
    const int srow = tid >> 3;           // 0..31
    const int scol = (tid & 7) * 8;      // 0..56

    short8 aq[2];
#pragma unroll
    for (int ks = 0; ks < 2; ++ks)
        aq[ks] = *(const short8*)&qkv[(rbase + q0 + wid * 16 + l15) * NQKV +
                                      hq + ks * 32 + lhi * 8];

    float mrun[4], lsum[4];
    f32x4 o[4] = {};
#pragma unroll
    for (int r = 0; r < 4; ++r) { mrun[r] = -INFINITY; lsum[r] = 0.f; }

    for (int st = 0; st < TT; st += 64) {
        __syncthreads();   // all waves done reading prev K/V tiles
#pragma unroll
        for (int ch = 0; ch < 2; ++ch)
            gld16(&qkv[(rbase + st + ch * 32 + srow) * NQKV + 1024 + hq + scol],
                  &Ks[ch * 2048 + wid * 512]);
#pragma unroll
        for (int ch = 0; ch < 2; ++ch)
            gld16(&vg[(size_t)(ch * 32 + srow) * TT + st + scol],
                  &Vs[ch * 2048 + wid * 512]);
        __syncthreads();   // tiles ready (vmcnt(0) drained by barrier)

        f32x4 s[4] = {};
#pragma unroll
        for (int nt = 0; nt < 4; ++nt)
#pragma unroll
            for (int ks = 0; ks < 2; ++ks) {
                short8 kf = *(const short8*)&Ks[(nt * 16 + l15) * 64 + ks * 32 + lhi * 8];
                s[nt] = __builtin_amdgcn_mfma_f32_16x16x32_bf16(aq[ks], kf, s[nt], 0, 0, 0);
            }
        float fac[4], p[4][4];
#pragma unroll
        for (int r = 0; r < 4; ++r) {
            float tmax = fmaxf(fmaxf(s[0][r], s[1][r]), fmaxf(s[2][r], s[3][r]));
#pragma unroll
            for (int off = 1; off < 16; off <<= 1)
                tmax = fmaxf(tmax, __shfl_xor(tmax, off, 16));
            float mnew = fmaxf(mrun[r], tmax);
            fac[r] = __expf(mrun[r] - mnew);
            float rs = 0.f;
#pragma unroll
            for (int nt = 0; nt < 4; ++nt) {
                p[nt][r] = __expf(s[nt][r] - mnew);
                rs += p[nt][r];
            }
#pragma unroll
            for (int off = 1; off < 16; off <<= 1) rs += __shfl_xor(rs, off, 16);
            lsum[r] = lsum[r] * fac[r] + rs;
            mrun[r] = mnew;
        }
#pragma unroll
        for (int dt = 0; dt < 4; ++dt)
#pragma unroll
            for (int r = 0; r < 4; ++r) o[dt][r] *= fac[r];

        // P bounce through per-wave LDS buffer (wave-local; lgkmcnt orders RAW)
#pragma unroll
        for (int nt = 0; nt < 4; ++nt)
#pragma unroll
            for (int r = 0; r < 4; ++r)
                Pl[wid][lhi * 4 + r][nt * 16 + l15] = f2bf(p[nt][r]);
        short8 pa[2];
        pa[0] = *(const short8*)&Pl[wid][l15][lhi * 8];
        pa[1] = *(const short8*)&Pl[wid][l15][32 + lhi * 8];
#pragma unroll
        for (int dt = 0; dt < 4; ++dt)
#pragma unroll
            for (int k2 = 0; k2 < 2; ++k2) {
                short8 vf = *(const short8*)&Vs[(dt * 16 + l15) * 64 + k2 * 32 + lhi * 8];
                o[dt] = __builtin_amdgcn_mfma_f32_16x16x32_bf16(pa[k2], vf, o[dt], 0, 0, 0);
            }
    }
#pragma unroll
    for (int r = 0; r < 4; ++r) lsum[r] = 1.0f / lsum[r];
#pragma unroll
    for (int dt = 0; dt < 4; ++dt)
#pragma unroll
        for (int r = 0; r < 4; ++r)
            obuf[(rbase + q0 + wid * 16 + lhi * 4 + r) * EE + hq + dt * 16 + l15] =
                f2bf(o[dt][r] * lsum[r]);
}

// ---------------- launch ----------------
extern "C" void kernel_launch(void* const* d_in, const int* in_sizes, int n_in,
                              void* d_out, int out_size, void* d_ws, size_t ws_size,
                              hipStream_t stream) {
    const float* x   = (const float*)d_in[0];
    const float* g1  = (const float*)d_in[1];
    const float* be1 = (const float*)d_in[2];
    const float* Wq  = (const float*)d_in[3];
    const float* Wk  = (const float*)d_in[4];
    const float* Wv  = (const float*)d_in[5];
    const float* Wp  = (const float*)d_in[6];
    const float* bp  = (const float*)d_in[7];
    const float* g2  = (const float*)d_in[8];
    const float* be2 = (const float*)d_in[9];
    const float* W1  = (const float*)d_in[10];
    const float* b1f = (const float*)d_in[11];
    const float* W2  = (const float*)d_in[12];
    const float* b2f = (const float*)d_in[13];

    char* p = (char*)d_ws;
    short* h_bf   = (short*)p; p += (size_t)MM * EE * 2;
    short* wqkv   = (short*)p; p += (size_t)EE * NQKV * 2;   // [3072][1024] W^T
    short* qkv    = (short*)p; p += (size_t)MM * NQKV * 2;
    short* o_bf   = (short*)p; p += (size_t)MM * EE * 2;
    short* wp_bf  = (short*)p; p += (size_t)EE * EE * 2;     // [1024][1024] Wp^T
    float* x1     = (float*)p; p += (size_t)MM * EE * 4;
    short* h2_bf  = (short*)p; p += (size_t)MM * EE * 2;
    short* w1_bf  = (short*)p; p += (size_t)EE * E4 * 2;     // [4096][1024] W1^T
    short* mid_bf = (short*)p; p += (size_t)MM * E4 * 2;
    short* w2_bf  = (short*)p; p += (size_t)E4 * EE * 2;     // [1024][4096] W2^T
    short* vTb    = (short*)p; p += (size_t)BB * 1024 * TT * 2;  // [b][h*64+d][t]

    pack_qkv_t<<<dim3(16, 48), 256, 0, stream>>>(Wq, Wk, Wv, wqkv);
    tcvt_kernel<<<dim3(16, 16), 256, 0, stream>>>(Wp, wp_bf, EE, EE);
    tcvt_kernel<<<dim3(64, 16), 256, 0, stream>>>(W1, w1_bf, EE, E4);
    tcvt_kernel<<<dim3(16, 64), 256, 0, stream>>>(W2, w2_bf, E4, EE);

    ln_kernel<<<MM, 256, 0, stream>>>(x, g1, be1, h_bf);

    gemm_bt<128, false, false, false, true>
        <<<dim3(NQKV / 128, MM / 128), 256, 0, stream>>>(h_bf, wqkv, nullptr, nullptr,
                                                         qkv, MM, NQKV, EE);

    vtr_kernel<<<dim3(16, 16, BB), 256, 0, stream>>>(qkv, vTb);

    attn_kernel<<<BB * HH * (TT / 64), 256, 0, stream>>>(qkv, vTb, o_bf);

    gemm_bt<64, true, false, true, false>
        <<<dim3(EE / 64, MM / 128), 256, 0, stream>>>(o_bf, wp_bf, bp, x, x1, MM, EE, EE);

    ln_kernel<<<MM, 256, 0, stream>>>(x1, g2, be2, h2_bf);

    gemm_bt<128, true, true, false, true>
        <<<dim3(E4 / 128, MM / 128), 256, 0, stream>>>(h2_bf, w1_bf, b1f, nullptr,
                                                       mid_bf, MM, E4, EE);

    gemm_bt<64, true, false, true, false>
        <<<dim3(EE / 64, MM / 128), 256, 0, stream>>>(mid_bf, w2_bf, b2f, x1,
                                                      (float*)d_out, MM, EE, E4);
}

// Round 5
// 299.515 us; speedup vs baseline: 1.1666x; 1.0139x over previous
//
#include <hip/hip_runtime.h>
#include <hip/hip_bf16.h>

// Problem constants (B,T,E,H,D) = (4,1024,1024,16,64)
#define BB 4
#define TT 1024
#define EE 1024
#define HH 16
#define DD 64
#define MM 4096    // B*T rows
#define NQKV 3072  // q|k|v packed cols
#define E4 4096    // 4*E

using short8  = __attribute__((ext_vector_type(8))) short;
using short4v = __attribute__((ext_vector_type(4))) short;
using f32x4   = __attribute__((ext_vector_type(4))) float;

__device__ __forceinline__ short f2bf(float f) {
    __hip_bfloat16 h = __float2bfloat16(f);
    return *reinterpret_cast<short*>(&h);
}

// async global->LDS, 16B per lane. LDS dest is wave-uniform base + lane*16.
__device__ __forceinline__ void gld16(const void* g, void* l) {
    __builtin_amdgcn_global_load_lds((__attribute__((address_space(1))) void*)g,
                                     (__attribute__((address_space(3))) void*)l,
                                     16, 0, 0);
}

// ---------------- transpose + convert: in fp32 [R][C] -> out bf16 [C][R] ----------------
__global__ __launch_bounds__(256) void tcvt_kernel(const float* __restrict__ in,
                                                   short* __restrict__ out,
                                                   int R, int C) {
    __shared__ short tile[64][65];
    const int c0 = blockIdx.x * 64, r0 = blockIdx.y * 64;
    const int tr = threadIdx.x >> 6;   // 0..3
    const int tc = threadIdx.x & 63;
#pragma unroll
    for (int i = 0; i < 16; ++i) {
        int r = i * 4 + tr;
        tile[tc][r] = f2bf(in[(size_t)(r0 + r) * C + c0 + tc]);
    }
    __syncthreads();
#pragma unroll
    for (int i = 0; i < 16; ++i) {
        int c = i * 4 + tr;
        out[(size_t)(c0 + c) * R + r0 + tc] = tile[c][tc];
    }
}

// pack Wq/Wk/Wv (H,E,D) -> bf16 W^T layout [3072][1024]: row = which*1024+head*64+d, col = e
__global__ __launch_bounds__(256) void pack_qkv_t(const float* __restrict__ Wq,
                                                  const float* __restrict__ Wk,
                                                  const float* __restrict__ Wv,
                                                  short* __restrict__ out) {
    __shared__ short tile[64][65];
    const int m = blockIdx.y;            // 0..47
    const int which = m >> 4, head = m & 15;
    const float* src = ((which == 0) ? Wq : (which == 1) ? Wk : Wv) + (size_t)head * EE * DD;
    const int e0 = blockIdx.x * 64;
    const int tr = threadIdx.x >> 6, tc = threadIdx.x & 63;
#pragma unroll
    for (int i = 0; i < 16; ++i) {
        int e = i * 4 + tr;
        tile[tc][e] = f2bf(src[(size_t)(e0 + e) * DD + tc]);   // tile[d][e_local]
    }
    __syncthreads();
#pragma unroll
    for (int i = 0; i < 16; ++i) {
        int d = i * 4 + tr;
        out[(size_t)(which * 1024 + head * 64 + d) * EE + e0 + tc] = tile[d][tc];
    }
}

// ---------------- V transpose: qkv V-part [b*T+t][2048 + c] -> vT[(b*1024+c)][t] ----------------
__global__ __launch_bounds__(256) void vtr_kernel(const short* __restrict__ qkv,
                                                  short* __restrict__ vT) {
    __shared__ short tile[64][68];
    const int b = blockIdx.z;
    const int t0 = blockIdx.x * 64, c0 = blockIdx.y * 64;
    const int tr = threadIdx.x >> 4;          // 0..15
    const int q4 = (threadIdx.x & 15) * 4;    // 0..60
#pragma unroll
    for (int i = 0; i < 4; ++i) {
        int t = i * 16 + tr;
        short4v v = *(const short4v*)&qkv[((size_t)b * TT + t0 + t) * NQKV + 2048 + c0 + q4];
        *(short4v*)&tile[t][q4] = v;
    }
    __syncthreads();
#pragma unroll
    for (int i = 0; i < 4; ++i) {
        int c = i * 16 + tr;
        short4v v;
        v[0] = tile[q4 + 0][c];
        v[1] = tile[q4 + 1][c];
        v[2] = tile[q4 + 2][c];
        v[3] = tile[q4 + 3][c];
        *(short4v*)&vT[((size_t)b * 1024 + c0 + c) * TT + t0 + q4] = v;
    }
}

// ---------------- LayerNorm (fp32 in -> bf16 out) ----------------
__global__ __launch_bounds__(256) void ln_kernel(const float* __restrict__ x,
                                                 const float* __restrict__ g,
                                                 const float* __restrict__ b,
                                                 short* __restrict__ out) {
    __shared__ float red[4];
    const int row = blockIdx.x;
    const int tid = threadIdx.x;
    float4 v = *(const float4*)&x[(size_t)row * EE + tid * 4];
    float s = v.x + v.y + v.z + v.w;
#pragma unroll
    for (int off = 32; off >= 1; off >>= 1) s += __shfl_xor(s, off, 64);
    if ((tid & 63) == 0) red[tid >> 6] = s;
    __syncthreads();
    float mean = (red[0] + red[1] + red[2] + red[3]) * (1.0f / EE);
    __syncthreads();
    float d0 = v.x - mean, d1 = v.y - mean, d2 = v.z - mean, d3 = v.w - mean;
    s = d0 * d0 + d1 * d1 + d2 * d2 + d3 * d3;
#pragma unroll
    for (int off = 32; off >= 1; off >>= 1) s += __shfl_xor(s, off, 64);
    if ((tid & 63) == 0) red[tid >> 6] = s;
    __syncthreads();
    float var = (red[0] + red[1] + red[2] + red[3]) * (1.0f / EE);
    float rstd = rsqrtf(var + 1e-5f);
    int c = tid * 4;
    short4v o;
    o[0] = f2bf(d0 * rstd * g[c + 0] + b[c + 0]);
    o[1] = f2bf(d1 * rstd * g[c + 1] + b[c + 1]);
    o[2] = f2bf(d2 * rstd * g[c + 2] + b[c + 2]);
    o[3] = f2bf(d3 * rstd * g[c + 3] + b[c + 3]);
    *(short4v*)&out[(size_t)row * EE + c] = o;
}

// ---------------- bf16 GEMM (m97 structure + T1 XCD swizzle) ----------------
template <int BN, bool HAS_BIAS, bool RELU, bool RESID, bool OUT_BF16>
__global__ __launch_bounds__(256) void gemm_bt(const short* __restrict__ A,
                                               const short* __restrict__ Bt,
                                               const float* __restrict__ bias,
                                               const float* __restrict__ resid,
                                               void* __restrict__ outp,
                                               int M, int N, int K) {
    constexpr int WRC = (BN == 128) ? 2 : 4;
    constexpr int WCC = (BN == 128) ? 2 : 1;
    constexpr int MI = 8 / WRC;
    constexpr int NI = BN / (16 * WCC);
    constexpr int BCH = BN / 32;

    __shared__ __align__(16) short As[128 * 64];
    __shared__ __align__(16) short Bs[BN * 64];

    const int tid = threadIdx.x;
    const int lane = tid & 63;
    const int wid = tid >> 6;
    const int wr = (WRC == 2) ? (wid >> 1) : wid;
    const int wc = (WCC == 2) ? (wid & 1) : 0;
    const int l15 = lane & 15, lhi = lane >> 4;

    // T1: XCD-aware bijective remap (all grids divisible by 8)
    int wg = blockIdx.y * gridDim.x + blockIdx.x;
    const int chunk = (gridDim.x * gridDim.y) >> 3;
    wg = (wg & 7) * chunk + (wg >> 3);
    const int bx = wg % gridDim.x;
    const int by = wg / gridDim.x;
    const int row0 = by * 128, col0 = bx * BN;

    const int srow = tid >> 3;
    const int scol = (tid & 7) * 8;

    const int wrow0 = wr * (16 * MI);
    const int wcol0 = wc * (16 * NI);

    f32x4 acc[MI][NI] = {};

    for (int k0 = 0; k0 < K; k0 += 64) {
        __syncthreads();
#pragma unroll
        for (int ch = 0; ch < 4; ++ch)
            gld16(&A[(size_t)(row0 + ch * 32 + srow) * K + k0 + scol],
                  &As[ch * 2048 + wid * 512]);
#pragma unroll
        for (int ch = 0; ch < BCH; ++ch)
            gld16(&Bt[(size_t)(col0 + ch * 32 + srow) * K + k0 + scol],
                  &Bs[ch * 2048 + wid * 512]);
        __syncthreads();
#pragma unroll
        for (int ks = 0; ks < 2; ++ks) {
            short8 af[MI], bf[NI];
#pragma unroll
            for (int mi = 0; mi < MI; ++mi)
                af[mi] = *(const short8*)&As[(wrow0 + mi * 16 + l15) * 64 + ks * 32 + lhi * 8];
#pragma unroll
            for (int ni = 0; ni < NI; ++ni)
                bf[ni] = *(const short8*)&Bs[(wcol0 + ni * 16 + l15) * 64 + ks * 32 + lhi * 8];
#pragma unroll
            for (int mi = 0; mi < MI; ++mi)
#pragma unroll
                for (int ni = 0; ni < NI; ++ni)
                    acc[mi][ni] = __builtin_amdgcn_mfma_f32_16x16x32_bf16(
                        af[mi], bf[ni], acc[mi][ni], 0, 0, 0);
        }
    }

    float* outf = (float*)outp;
    short* outb = (short*)outp;
#pragma unroll
    for (int mi = 0; mi < MI; ++mi)
#pragma unroll
        for (int ni = 0; ni < NI; ++ni)
#pragma unroll
            for (int r = 0; r < 4; ++r) {
                int row = row0 + wrow0 + mi * 16 + lhi * 4 + r;
                int col = col0 + wcol0 + ni * 16 + l15;
                float v = acc[mi][ni][r];
                if (HAS_BIAS) v += bias[col];
                if (RELU) v = fmaxf(v, 0.f);
                if (RESID) v += resid[(size_t)row * N + col];
                if (OUT_BF16) outb[(size_t)row * N + col] = f2bf(v);
                else outf[(size_t)row * N + col] = v;
            }
}

// ---------------- flash attention (4 waves x 32 q-rows, dbuf K/V, swizzled LDS) ----------------
// QBLK=128, KVBLK=64. K staged [kv][d], V staged [d][kv], both with 16B-slot
// XOR swizzle (slot ^= row&7) applied on the GLOBAL source (LDS stays linear
// for global_load_lds) and on the ds_read address. Double-buffered, one
// barrier per tile (syncthreads drains vmcnt). Defer-max online softmax (THR=8).
__global__ __launch_bounds__(256) void attn_kernel(const short* __restrict__ qkv,
                                                   const short* __restrict__ vT,
                                                   short* __restrict__ obuf) {
    __shared__ __align__(16) short Ks[2][64 * 64];
    __shared__ __align__(16) short Vs[2][64 * 64];
    __shared__ short Pl[4][16][72];
    const int tid = threadIdx.x;
    const int lane = tid & 63;
    const int wid = tid >> 6;
    const int l15 = lane & 15, lhi = lane >> 4;

    // T1: XCD swizzle; 512 blocks, 8 q-blocks per (b,h) stay on one XCD
    const int nb = ((blockIdx.x & 7) << 6) + (blockIdx.x >> 3);
    const int b = nb >> 7;
    const int h = (nb >> 3) & 15;
    const int q0 = (nb & 7) << 7;     // *128
    const size_t rbase = (size_t)b * TT;
    const int hq = h * 64;
    const short* vg = vT + ((size_t)b * 1024 + hq) * TT;

    const int srow = tid >> 3;                      // 0..31
    const int sslot = tid & 7;                      // 16B slot
    const int scol = ((sslot ^ (srow & 7)) << 3);   // swizzled source col (elems)
    const int rsw = (l15 & 7);                      // read-side row swizzle key

    // Q fragments: 2 groups of 16 q-rows per wave (wave owns rows q0+wid*32..+32)
    short8 aq[2][2];
#pragma unroll
    for (int g = 0; g < 2; ++g)
#pragma unroll
        for (int ks = 0; ks < 2; ++ks)
            aq[g][ks] = *(const short8*)&qkv[(rbase + q0 + wid * 32 + g * 16 + l15) * NQKV +
                                             hq + ks * 32 + lhi * 8];

    float mrun[2][4], lsum[2][4];
    f32x4 o[2][4] = {};
#pragma unroll
    for (int g = 0; g < 2; ++g)
#pragma unroll
        for (int r = 0; r < 4; ++r) { mrun[g][r] = -INFINITY; lsum[g][r] = 0.f; }

    // prologue: stage tile 0 into buf 0
#pragma unroll
    for (int ch = 0; ch < 2; ++ch) {
        gld16(&qkv[(rbase + 0 + ch * 32 + srow) * NQKV + 1024 + hq + scol],
              &Ks[0][ch * 2048 + wid * 512]);
        gld16(&vg[(size_t)(ch * 32 + srow) * TT + 0 + scol],
              &Vs[0][ch * 2048 + wid * 512]);
    }
    __syncthreads();   // drains vmcnt -> tile 0 ready

    int cur = 0;
    for (int st = 0; st < TT; st += 64) {
        // prefetch next tile into other buffer (overlaps with compute below)
        if (st + 64 < TT) {
#pragma unroll
            for (int ch = 0; ch < 2; ++ch) {
                gld16(&qkv[(rbase + st + 64 + ch * 32 + srow) * NQKV + 1024 + hq + scol],
                      &Ks[cur ^ 1][ch * 2048 + wid * 512]);
                gld16(&vg[(size_t)(ch * 32 + srow) * TT + st + 64 + scol],
                      &Vs[cur ^ 1][ch * 2048 + wid * 512]);
            }
        }
        const short* K = &Ks[cur][0];
        const short* V = &Vs[cur][0];

#pragma unroll
        for (int g = 0; g < 2; ++g) {
            f32x4 s[4] = {};
#pragma unroll
            for (int nt = 0; nt < 4; ++nt)
#pragma unroll
                for (int ks = 0; ks < 2; ++ks) {
                    short8 kf = *(const short8*)&K[(nt * 16 + l15) * 64 +
                                                   (((ks << 2) + lhi) ^ rsw) * 8];
                    s[nt] = __builtin_amdgcn_mfma_f32_16x16x32_bf16(aq[g][ks], kf,
                                                                    s[nt], 0, 0, 0);
                }
            // tile max per q-row (reduce over l15 lanes, width 16)
            float tmax4[4], need = 0.f;
#pragma unroll
            for (int r = 0; r < 4; ++r) {
                float tmax = fmaxf(fmaxf(s[0][r], s[1][r]), fmaxf(s[2][r], s[3][r]));
#pragma unroll
                for (int off = 1; off < 16; off <<= 1)
                    tmax = fmaxf(tmax, __shfl_xor(tmax, off, 16));
                tmax4[r] = tmax;
                need = fmaxf(need, tmax - mrun[g][r]);
            }
            // T13 defer-max: rescale only when some row grew by > 8
            const bool full = !__all(need <= 8.0f);
            float fac[4];
            if (full) {
#pragma unroll
                for (int r = 0; r < 4; ++r) {
                    float mnew = fmaxf(mrun[g][r], tmax4[r]);
                    fac[r] = __expf(mrun[g][r] - mnew);
                    mrun[g][r] = mnew;
                }
            }
            float p[4][4];
#pragma unroll
            for (int r = 0; r < 4; ++r) {
                float rs = 0.f;
#pragma unroll
                for (int nt = 0; nt < 4; ++nt) {
                    p[nt][r] = __expf(s[nt][r] - mrun[g][r]);
                    rs += p[nt][r];
                }
#pragma unroll
                for (int off = 1; off < 16; off <<= 1) rs += __shfl_xor(rs, off, 16);
                lsum[g][r] = (full ? lsum[g][r] * fac[r] : lsum[g][r]) + rs;
            }
            if (full) {
#pragma unroll
                for (int dt = 0; dt < 4; ++dt)
#pragma unroll
                    for (int r = 0; r < 4; ++r) o[g][dt][r] *= fac[r];
            }
            // P bounce through per-wave LDS (C-layout -> A-frag layout)
#pragma unroll
            for (int nt = 0; nt < 4; ++nt)
#pragma unroll
                for (int r = 0; r < 4; ++r)
                    Pl[wid][lhi * 4 + r][nt * 16 + l15] = f2bf(p[nt][r]);
            short8 pa[2];
            pa[0] = *(const short8*)&Pl[wid][l15][lhi * 8];
            pa[1] = *(const short8*)&Pl[wid][l15][32 + lhi * 8];
#pragma unroll
            for (int dt = 0; dt < 4; ++dt)
#pragma unroll
                for (int k2 = 0; k2 < 2; ++k2) {
                    short8 vf = *(const short8*)&V[(dt * 16 + l15) * 64 +
                                                   (((k2 << 2) + lhi) ^ rsw) * 8];
                    o[g][dt] = __builtin_amdgcn_mfma_f32_16x16x32_bf16(pa[k2], vf,
                                                                       o[g][dt], 0, 0, 0);
                }
        }
        __syncthreads();   // all waves done with buf[cur]; prefetch drained
        cur ^= 1;
    }
#pragma unroll
    for (int g = 0; g < 2; ++g) {
#pragma unroll
        for (int r = 0; r < 4; ++r) lsum[g][r] = 1.0f / lsum[g][r];
#pragma unroll
        for (int dt = 0; dt < 4; ++dt)
#pragma unroll
            for (int r = 0; r < 4; ++r)
                obuf[(rbase + q0 + wid * 32 + g * 16 + lhi * 4 + r) * EE +
                     hq + dt * 16 + l15] = f2bf(o[g][dt][r] * lsum[g][r]);
    }
}

// ---------------- launch ----------------
extern "C" void kernel_launch(void* const* d_in, const int* in_sizes, int n_in,
                              void* d_out, int out_size, void* d_ws, size_t ws_size,
                              hipStream_t stream) {
    const float* x   = (const float*)d_in[0];
    const float* g1  = (const float*)d_in[1];
    const float* be1 = (const float*)d_in[2];
    const float* Wq  = (const float*)d_in[3];
    const float* Wk  = (const float*)d_in[4];
    const float* Wv  = (const float*)d_in[5];
    const float* Wp  = (const float*)d_in[6];
    const float* bp  = (const float*)d_in[7];
    const float* g2  = (const float*)d_in[8];
    const float* be2 = (const float*)d_in[9];
    const float* W1  = (const float*)d_in[10];
    const float* b1f = (const float*)d_in[11];
    const float* W2  = (const float*)d_in[12];
    const float* b2f = (const float*)d_in[13];

    char* p = (char*)d_ws;
    short* h_bf   = (short*)p; p += (size_t)MM * EE * 2;
    short* wqkv   = (short*)p; p += (size_t)EE * NQKV * 2;   // [3072][1024] W^T
    short* qkv    = (short*)p; p += (size_t)MM * NQKV * 2;
    short* o_bf   = (short*)p; p += (size_t)MM * EE * 2;
    short* wp_bf  = (short*)p; p += (size_t)EE * EE * 2;     // [1024][1024] Wp^T
    float* x1     = (float*)p; p += (size_t)MM * EE * 4;
    short* h2_bf  = (short*)p; p += (size_t)MM * EE * 2;
    short* w1_bf  = (short*)p; p += (size_t)EE * E4 * 2;     // [4096][1024] W1^T
    short* mid_bf = (short*)p; p += (size_t)MM * E4 * 2;
    short* w2_bf  = (short*)p; p += (size_t)E4 * EE * 2;     // [1024][4096] W2^T
    short* vTb    = (short*)p; p += (size_t)BB * 1024 * TT * 2;  // [b][h*64+d][t]

    pack_qkv_t<<<dim3(16, 48), 256, 0, stream>>>(Wq, Wk, Wv, wqkv);
    tcvt_kernel<<<dim3(16, 16), 256, 0, stream>>>(Wp, wp_bf, EE, EE);
    tcvt_kernel<<<dim3(64, 16), 256, 0, stream>>>(W1, w1_bf, EE, E4);
    tcvt_kernel<<<dim3(16, 64), 256, 0, stream>>>(W2, w2_bf, E4, EE);

    ln_kernel<<<MM, 256, 0, stream>>>(x, g1, be1, h_bf);

    gemm_bt<128, false, false, false, true>
        <<<dim3(NQKV / 128, MM / 128), 256, 0, stream>>>(h_bf, wqkv, nullptr, nullptr,
                                                         qkv, MM, NQKV, EE);

    vtr_kernel<<<dim3(16, 16, BB), 256, 0, stream>>>(qkv, vTb);

    attn_kernel<<<BB * HH * (TT / 128), 256, 0, stream>>>(qkv, vTb, o_bf);

    gemm_bt<64, true, false, true, false>
        <<<dim3(EE / 64, MM / 128), 256, 0, stream>>>(o_bf, wp_bf, bp, x, x1, MM, EE, EE);

    ln_kernel<<<MM, 256, 0, stream>>>(x1, g2, be2, h2_bf);

    gemm_bt<128, true, true, false, true>
        <<<dim3(E4 / 128, MM / 128), 256, 0, stream>>>(h2_bf, w1_bf, b1f, nullptr,
                                                       mid_bf, MM, E4, EE);

    gemm_bt<64, true, false, true, false>
        <<<dim3(EE / 64, MM / 128), 256, 0, stream>>>(mid_bf, w2_bf, b2f, x1,
                                                      (float*)d_out, MM, EE, E4);
}

// Round 6
// 254.077 us; speedup vs baseline: 1.3752x; 1.1788x over previous
//
#include <hip/hip_runtime.h>
#include <hip/hip_bf16.h>

// Problem constants (B,T,E,H,D) = (4,1024,1024,16,64)
#define BB 4
#define TT 1024
#define EE 1024
#define HH 16
#define DD 64
#define MM 4096    // B*T rows
#define NQKV 3072  // q|k|v packed cols
#define E4 4096    // 4*E

using short8  = __attribute__((ext_vector_type(8))) short;
using short4v = __attribute__((ext_vector_type(4))) short;
using f32x4   = __attribute__((ext_vector_type(4))) float;

__device__ __forceinline__ short f2bf(float f) {
    __hip_bfloat16 h = __float2bfloat16(f);
    return *reinterpret_cast<short*>(&h);
}

// async global->LDS, 16B per lane. LDS dest is wave-uniform base + lane*16.
__device__ __forceinline__ void gld16(const void* g, void* l) {
    __builtin_amdgcn_global_load_lds((__attribute__((address_space(1))) void*)g,
                                     (__attribute__((address_space(3))) void*)l,
                                     16, 0, 0);
}

// ---------------- transpose + convert: in fp32 [R][C] -> out bf16 [C][R] ----------------
__global__ __launch_bounds__(256) void tcvt_kernel(const float* __restrict__ in,
                                                   short* __restrict__ out,
                                                   int R, int C) {
    __shared__ short tile[64][65];
    const int c0 = blockIdx.x * 64, r0 = blockIdx.y * 64;
    const int tr = threadIdx.x >> 6;   // 0..3
    const int tc = threadIdx.x & 63;
#pragma unroll
    for (int i = 0; i < 16; ++i) {
        int r = i * 4 + tr;
        tile[tc][r] = f2bf(in[(size_t)(r0 + r) * C + c0 + tc]);
    }
    __syncthreads();
#pragma unroll
    for (int i = 0; i < 16; ++i) {
        int c = i * 4 + tr;
        out[(size_t)(c0 + c) * R + r0 + tc] = tile[c][tc];
    }
}

// pack Wq/Wk/Wv (H,E,D) -> bf16 W^T layout [3072][1024]: row = which*1024+head*64+d, col = e
__global__ __launch_bounds__(256) void pack_qkv_t(const float* __restrict__ Wq,
                                                  const float* __restrict__ Wk,
                                                  const float* __restrict__ Wv,
                                                  short* __restrict__ out) {
    __shared__ short tile[64][65];
    const int m = blockIdx.y;            // 0..47
    const int which = m >> 4, head = m & 15;
    const float* src = ((which == 0) ? Wq : (which == 1) ? Wk : Wv) + (size_t)head * EE * DD;
    const int e0 = blockIdx.x * 64;
    const int tr = threadIdx.x >> 6, tc = threadIdx.x & 63;
#pragma unroll
    for (int i = 0; i < 16; ++i) {
        int e = i * 4 + tr;
        tile[tc][e] = f2bf(src[(size_t)(e0 + e) * DD + tc]);   // tile[d][e_local]
    }
    __syncthreads();
#pragma unroll
    for (int i = 0; i < 16; ++i) {
        int d = i * 4 + tr;
        out[(size_t)(which * 1024 + head * 64 + d) * EE + e0 + tc] = tile[d][tc];
    }
}

// ---------------- V transpose: qkv V-part [b*T+t][2048 + c] -> vT[(b*1024+c)][t] ----------------
__global__ __launch_bounds__(256) void vtr_kernel(const short* __restrict__ qkv,
                                                  short* __restrict__ vT) {
    __shared__ short tile[64][68];
    const int b = blockIdx.z;
    const int t0 = blockIdx.x * 64, c0 = blockIdx.y * 64;
    const int tr = threadIdx.x >> 4;          // 0..15
    const int q4 = (threadIdx.x & 15) * 4;    // 0..60
#pragma unroll
    for (int i = 0; i < 4; ++i) {
        int t = i * 16 + tr;
        short4v v = *(const short4v*)&qkv[((size_t)b * TT + t0 + t) * NQKV + 2048 + c0 + q4];
        *(short4v*)&tile[t][q4] = v;
    }
    __syncthreads();
#pragma unroll
    for (int i = 0; i < 4; ++i) {
        int c = i * 16 + tr;
        short4v v;
        v[0] = tile[q4 + 0][c];
        v[1] = tile[q4 + 1][c];
        v[2] = tile[q4 + 2][c];
        v[3] = tile[q4 + 3][c];
        *(short4v*)&vT[((size_t)b * 1024 + c0 + c) * TT + t0 + q4] = v;
    }
}

// ---------------- LayerNorm (fp32 in -> bf16 out) ----------------
__global__ __launch_bounds__(256) void ln_kernel(const float* __restrict__ x,
                                                 const float* __restrict__ g,
                                                 const float* __restrict__ b,
                                                 short* __restrict__ out) {
    __shared__ float red[4];
    const int row = blockIdx.x;
    const int tid = threadIdx.x;
    float4 v = *(const float4*)&x[(size_t)row * EE + tid * 4];
    float s = v.x + v.y + v.z + v.w;
#pragma unroll
    for (int off = 32; off >= 1; off >>= 1) s += __shfl_xor(s, off, 64);
    if ((tid & 63) == 0) red[tid >> 6] = s;
    __syncthreads();
    float mean = (red[0] + red[1] + red[2] + red[3]) * (1.0f / EE);
    __syncthreads();
    float d0 = v.x - mean, d1 = v.y - mean, d2 = v.z - mean, d3 = v.w - mean;
    s = d0 * d0 + d1 * d1 + d2 * d2 + d3 * d3;
#pragma unroll
    for (int off = 32; off >= 1; off >>= 1) s += __shfl_xor(s, off, 64);
    if ((tid & 63) == 0) red[tid >> 6] = s;
    __syncthreads();
    float var = (red[0] + red[1] + red[2] + red[3]) * (1.0f / EE);
    float rstd = rsqrtf(var + 1e-5f);
    int c = tid * 4;
    short4v o;
    o[0] = f2bf(d0 * rstd * g[c + 0] + b[c + 0]);
    o[1] = f2bf(d1 * rstd * g[c + 1] + b[c + 1]);
    o[2] = f2bf(d2 * rstd * g[c + 2] + b[c + 2]);
    o[3] = f2bf(d3 * rstd * g[c + 3] + b[c + 3]);
    *(short4v*)&out[(size_t)row * EE + c] = o;
}

// ---------------- bf16 GEMM: C[M,N] = A[M,K] @ B[K,N], Bt = B^T [N][K] ----------------
// m97 structure + T1 XCD swizzle + T2 slot-swizzle (pre-swizzled global source,
// linear LDS, XOR'd ds_read). DBUF: double-buffered K-tiles (prefetch-before-
// compute, one barrier per K-step) for grid-capped-occupancy shapes (BN=64).
template <int BN, bool DBUF, bool HAS_BIAS, bool RELU, bool RESID, bool OUT_BF16>
__global__ __launch_bounds__(256) void gemm_bt(const short* __restrict__ A,
                                               const short* __restrict__ Bt,
                                               const float* __restrict__ bias,
                                               const float* __restrict__ resid,
                                               void* __restrict__ outp,
                                               int M, int N, int K) {
    constexpr int WRC = (BN == 128) ? 2 : 4;
    constexpr int WCC = (BN == 128) ? 2 : 1;
    constexpr int MI = 8 / WRC;
    constexpr int NI = BN / (16 * WCC);
    constexpr int BCH = BN / 32;
    constexpr int ASZ = 128 * 64, BSZ = BN * 64;

    __shared__ __align__(16) short As[(DBUF ? 2 : 1) * ASZ];
    __shared__ __align__(16) short Bs[(DBUF ? 2 : 1) * BSZ];

    const int tid = threadIdx.x;
    const int lane = tid & 63;
    const int wid = tid >> 6;
    const int wr = (WRC == 2) ? (wid >> 1) : wid;
    const int wc = (WCC == 2) ? (wid & 1) : 0;
    const int l15 = lane & 15, lhi = lane >> 4;

    // T1: XCD-aware bijective remap (all grids divisible by 8)
    int wg = blockIdx.y * gridDim.x + blockIdx.x;
    const int chunk = (gridDim.x * gridDim.y) >> 3;
    wg = (wg & 7) * chunk + (wg >> 3);
    const int bx = wg % gridDim.x;
    const int by = wg / gridDim.x;
    const int row0 = by * 128, col0 = bx * BN;

    const int srow = tid >> 3;                            // 0..31
    const int scol = (((tid & 7) ^ (srow & 7)) << 3);     // swizzled source col
    const int rsw = l15 & 7;                              // read-side swizzle key

    const int wrow0 = wr * (16 * MI);
    const int wcol0 = wc * (16 * NI);

    f32x4 acc[MI][NI] = {};

    auto stage = [&](int k0, int bs) {
#pragma unroll
        for (int ch = 0; ch < 4; ++ch)
            gld16(&A[(size_t)(row0 + ch * 32 + srow) * K + k0 + scol],
                  &As[bs * ASZ + ch * 2048 + wid * 512]);
#pragma unroll
        for (int ch = 0; ch < BCH; ++ch)
            gld16(&Bt[(size_t)(col0 + ch * 32 + srow) * K + k0 + scol],
                  &Bs[bs * BSZ + ch * 2048 + wid * 512]);
    };
    auto compute = [&](int bs) {
#pragma unroll
        for (int ks = 0; ks < 2; ++ks) {
            short8 af[MI], bf[NI];
#pragma unroll
            for (int mi = 0; mi < MI; ++mi)
                af[mi] = *(const short8*)&As[bs * ASZ + (wrow0 + mi * 16 + l15) * 64 +
                                             (((ks << 2) + lhi) ^ rsw) * 8];
#pragma unroll
            for (int ni = 0; ni < NI; ++ni)
                bf[ni] = *(const short8*)&Bs[bs * BSZ + (wcol0 + ni * 16 + l15) * 64 +
                                             (((ks << 2) + lhi) ^ rsw) * 8];
#pragma unroll
            for (int mi = 0; mi < MI; ++mi)
#pragma unroll
                for (int ni = 0; ni < NI; ++ni)
                    acc[mi][ni] = __builtin_amdgcn_mfma_f32_16x16x32_bf16(
                        af[mi], bf[ni], acc[mi][ni], 0, 0, 0);
        }
    };

    if (DBUF) {
        stage(0, 0);
        __syncthreads();           // tile 0 ready
        int cur = 0;
        for (int k0 = 0; k0 < K; k0 += 64) {
            if (k0 + 64 < K) stage(k0 + 64, cur ^ 1);  // prefetch overlaps compute
            compute(cur);
            __syncthreads();       // readers done + prefetch drained
            cur ^= 1;
        }
    } else {
        for (int k0 = 0; k0 < K; k0 += 64) {
            __syncthreads();
            stage(k0, 0);
            __syncthreads();
            compute(0);
        }
    }

    float* outf = (float*)outp;
    short* outb = (short*)outp;
#pragma unroll
    for (int mi = 0; mi < MI; ++mi)
#pragma unroll
        for (int ni = 0; ni < NI; ++ni)
#pragma unroll
            for (int r = 0; r < 4; ++r) {
                int row = row0 + wrow0 + mi * 16 + lhi * 4 + r;
                int col = col0 + wcol0 + ni * 16 + l15;
                float v = acc[mi][ni][r];
                if (HAS_BIAS) v += bias[col];
                if (RELU) v = fmaxf(v, 0.f);
                if (RESID) v += resid[(size_t)row * N + col];
                if (OUT_BF16) outb[(size_t)row * N + col] = f2bf(v);
                else outf[(size_t)row * N + col] = v;
            }
}

// ---------------- flash attention (4 waves x 32 q-rows, dbuf K/V, swizzled LDS) ----------------
__global__ __launch_bounds__(256) void attn_kernel(const short* __restrict__ qkv,
                                                   const short* __restrict__ vT,
                                                   short* __restrict__ obuf) {
    __shared__ __align__(16) short Ks[2][64 * 64];
    __shared__ __align__(16) short Vs[2][64 * 64];
    __shared__ short Pl[4][16][72];
    const int tid = threadIdx.x;
    const int lane = tid & 63;
    const int wid = tid >> 6;
    const int l15 = lane & 15, lhi = lane >> 4;

    // T1: XCD swizzle; 8 q-blocks per (b,h) stay on one XCD
    const int nb = ((blockIdx.x & 7) << 6) + (blockIdx.x >> 3);
    const int b = nb >> 7;
    const int h = (nb >> 3) & 15;
    const int q0 = (nb & 7) << 7;     // *128
    const size_t rbase = (size_t)b * TT;
    const int hq = h * 64;
    const short* vg = vT + ((size_t)b * 1024 + hq) * TT;

    const int srow = tid >> 3;                      // 0..31
    const int sslot = tid & 7;                      // 16B slot
    const int scol = ((sslot ^ (srow & 7)) << 3);   // swizzled source col (elems)
    const int rsw = (l15 & 7);                      // read-side row swizzle key

    short8 aq[2][2];
#pragma unroll
    for (int g = 0; g < 2; ++g)
#pragma unroll
        for (int ks = 0; ks < 2; ++ks)
            aq[g][ks] = *(const short8*)&qkv[(rbase + q0 + wid * 32 + g * 16 + l15) * NQKV +
                                             hq + ks * 32 + lhi * 8];

    float mrun[2][4], lsum[2][4];
    f32x4 o[2][4] = {};
#pragma unroll
    for (int g = 0; g < 2; ++g)
#pragma unroll
        for (int r = 0; r < 4; ++r) { mrun[g][r] = -INFINITY; lsum[g][r] = 0.f; }

#pragma unroll
    for (int ch = 0; ch < 2; ++ch) {
        gld16(&qkv[(rbase + 0 + ch * 32 + srow) * NQKV + 1024 + hq + scol],
              &Ks[0][ch * 2048 + wid * 512]);
        gld16(&vg[(size_t)(ch * 32 + srow) * TT + 0 + scol],
              &Vs[0][ch * 2048 + wid * 512]);
    }
    __syncthreads();

    int cur = 0;
    for (int st = 0; st < TT; st += 64) {
        if (st + 64 < TT) {
#pragma unroll
            for (int ch = 0; ch < 2; ++ch) {
                gld16(&qkv[(rbase + st + 64 + ch * 32 + srow) * NQKV + 1024 + hq + scol],
                      &Ks[cur ^ 1][ch * 2048 + wid * 512]);
                gld16(&vg[(size_t)(ch * 32 + srow) * TT + st + 64 + scol],
                      &Vs[cur ^ 1][ch * 2048 + wid * 512]);
            }
        }
        const short* K = &Ks[cur][0];
        const short* V = &Vs[cur][0];

#pragma unroll
        for (int g = 0; g < 2; ++g) {
            f32x4 s[4] = {};
#pragma unroll
            for (int nt = 0; nt < 4; ++nt)
#pragma unroll
                for (int ks = 0; ks < 2; ++ks) {
                    short8 kf = *(const short8*)&K[(nt * 16 + l15) * 64 +
                                                   (((ks << 2) + lhi) ^ rsw) * 8];
                    s[nt] = __builtin_amdgcn_mfma_f32_16x16x32_bf16(aq[g][ks], kf,
                                                                    s[nt], 0, 0, 0);
                }
            float tmax4[4], need = 0.f;
#pragma unroll
            for (int r = 0; r < 4; ++r) {
                float tmax = fmaxf(fmaxf(s[0][r], s[1][r]), fmaxf(s[2][r], s[3][r]));
#pragma unroll
                for (int off = 1; off < 16; off <<= 1)
                    tmax = fmaxf(tmax, __shfl_xor(tmax, off, 16));
                tmax4[r] = tmax;
                need = fmaxf(need, tmax - mrun[g][r]);
            }
            const bool full = !__all(need <= 8.0f);
            float fac[4];
            if (full) {
#pragma unroll
                for (int r = 0; r < 4; ++r) {
                    float mnew = fmaxf(mrun[g][r], tmax4[r]);
                    fac[r] = __expf(mrun[g][r] - mnew);
                    mrun[g][r] = mnew;
                }
            }
            float p[4][4];
#pragma unroll
            for (int r = 0; r < 4; ++r) {
                float rs = 0.f;
#pragma unroll
                for (int nt = 0; nt < 4; ++nt) {
                    p[nt][r] = __expf(s[nt][r] - mrun[g][r]);
                    rs += p[nt][r];
                }
#pragma unroll
                for (int off = 1; off < 16; off <<= 1) rs += __shfl_xor(rs, off, 16);
                lsum[g][r] = (full ? lsum[g][r] * fac[r] : lsum[g][r]) + rs;
            }
            if (full) {
#pragma unroll
                for (int dt = 0; dt < 4; ++dt)
#pragma unroll
                    for (int r = 0; r < 4; ++r) o[g][dt][r] *= fac[r];
            }
#pragma unroll
            for (int nt = 0; nt < 4; ++nt)
#pragma unroll
                for (int r = 0; r < 4; ++r)
                    Pl[wid][lhi * 4 + r][nt * 16 + l15] = f2bf(p[nt][r]);
            short8 pa[2];
            pa[0] = *(const short8*)&Pl[wid][l15][lhi * 8];
            pa[1] = *(const short8*)&Pl[wid][l15][32 + lhi * 8];
#pragma unroll
            for (int dt = 0; dt < 4; ++dt)
#pragma unroll
                for (int k2 = 0; k2 < 2; ++k2) {
                    short8 vf = *(const short8*)&V[(dt * 16 + l15) * 64 +
                                                   (((k2 << 2) + lhi) ^ rsw) * 8];
                    o[g][dt] = __builtin_amdgcn_mfma_f32_16x16x32_bf16(pa[k2], vf,
                                                                       o[g][dt], 0, 0, 0);
                }
        }
        __syncthreads();
        cur ^= 1;
    }
#pragma unroll
    for (int g = 0; g < 2; ++g) {
#pragma unroll
        for (int r = 0; r < 4; ++r) lsum[g][r] = 1.0f / lsum[g][r];
#pragma unroll
        for (int dt = 0; dt < 4; ++dt)
#pragma unroll
            for (int r = 0; r < 4; ++r)
                obuf[(rbase + q0 + wid * 32 + g * 16 + lhi * 4 + r) * EE +
                     hq + dt * 16 + l15] = f2bf(o[g][dt][r] * lsum[g][r]);
    }
}

// ---------------- launch ----------------
extern "C" void kernel_launch(void* const* d_in, const int* in_sizes, int n_in,
                              void* d_out, int out_size, void* d_ws, size_t ws_size,
                              hipStream_t stream) {
    const float* x   = (const float*)d_in[0];
    const float* g1  = (const float*)d_in[1];
    const float* be1 = (const float*)d_in[2];
    const float* Wq  = (const float*)d_in[3];
    const float* Wk  = (const float*)d_in[4];
    const float* Wv  = (const float*)d_in[5];
    const float* Wp  = (const float*)d_in[6];
    const float* bp  = (const float*)d_in[7];
    const float* g2  = (const float*)d_in[8];
    const float* be2 = (const float*)d_in[9];
    const float* W1  = (const float*)d_in[10];
    const float* b1f = (const float*)d_in[11];
    const float* W2  = (const float*)d_in[12];
    const float* b2f = (const float*)d_in[13];

    char* p = (char*)d_ws;
    short* h_bf   = (short*)p; p += (size_t)MM * EE * 2;
    short* wqkv   = (short*)p; p += (size_t)EE * NQKV * 2;   // [3072][1024] W^T
    short* qkv    = (short*)p; p += (size_t)MM * NQKV * 2;
    short* o_bf   = (short*)p; p += (size_t)MM * EE * 2;
    short* wp_bf  = (short*)p; p += (size_t)EE * EE * 2;     // [1024][1024] Wp^T
    float* x1     = (float*)p; p += (size_t)MM * EE * 4;
    short* h2_bf  = (short*)p; p += (size_t)MM * EE * 2;
    short* w1_bf  = (short*)p; p += (size_t)EE * E4 * 2;     // [4096][1024] W1^T
    short* mid_bf = (short*)p; p += (size_t)MM * E4 * 2;
    short* w2_bf  = (short*)p; p += (size_t)E4 * EE * 2;     // [1024][4096] W2^T
    short* vTb    = (short*)p; p += (size_t)BB * 1024 * TT * 2;  // [b][h*64+d][t]

    pack_qkv_t<<<dim3(16, 48), 256, 0, stream>>>(Wq, Wk, Wv, wqkv);
    tcvt_kernel<<<dim3(16, 16), 256, 0, stream>>>(Wp, wp_bf, EE, EE);
    tcvt_kernel<<<dim3(64, 16), 256, 0, stream>>>(W1, w1_bf, EE, E4);
    tcvt_kernel<<<dim3(16, 64), 256, 0, stream>>>(W2, w2_bf, E4, EE);

    ln_kernel<<<MM, 256, 0, stream>>>(x, g1, be1, h_bf);

    gemm_bt<128, false, false, false, false, true>
        <<<dim3(NQKV / 128, MM / 128), 256, 0, stream>>>(h_bf, wqkv, nullptr, nullptr,
                                                         qkv, MM, NQKV, EE);

    vtr_kernel<<<dim3(16, 16, BB), 256, 0, stream>>>(qkv, vTb);

    attn_kernel<<<BB * HH * (TT / 128), 256, 0, stream>>>(qkv, vTb, o_bf);

    gemm_bt<64, true, true, false, true, false>
        <<<dim3(EE / 64, MM / 128), 256, 0, stream>>>(o_bf, wp_bf, bp, x, x1, MM, EE, EE);

    ln_kernel<<<MM, 256, 0, stream>>>(x1, g2, be2, h2_bf);

    gemm_bt<128, false, true, true, false, true>
        <<<dim3(E4 / 128, MM / 128), 256, 0, stream>>>(h2_bf, w1_bf, b1f, nullptr,
                                                       mid_bf, MM, E4, EE);

    gemm_bt<64, true, true, false, true, false>
        <<<dim3(EE / 64, MM / 128), 256, 0, stream>>>(mid_bf, w2_bf, b2f, x1,
                                                      (float*)d_out, MM, EE, E4);
}

// Round 7
// 238.029 us; speedup vs baseline: 1.4679x; 1.0674x over previous
//
#include <hip/hip_runtime.h>
#include <hip/hip_bf16.h>

// Problem constants (B,T,E,H,D) = (4,1024,1024,16,64)
#define BB 4
#define TT 1024
#define EE 1024
#define HH 16
#define DD 64
#define MM 4096    // B*T rows
#define NQKV 3072  // q|k|v packed cols
#define E4 4096    // 4*E

using short8  = __attribute__((ext_vector_type(8))) short;
using short4v = __attribute__((ext_vector_type(4))) short;
using f32x4   = __attribute__((ext_vector_type(4))) float;

__device__ __forceinline__ short f2bf(float f) {
    __hip_bfloat16 h = __float2bfloat16(f);
    return *reinterpret_cast<short*>(&h);
}

// pack two f32 -> one u32 of 2 bf16 (low = a, high = b); no builtin on gfx950
__device__ __forceinline__ unsigned int cvtpk_bf16(float a, float b) {
    unsigned int w;
    asm("v_cvt_pk_bf16_f32 %0, %1, %2" : "=v"(w) : "v"(a), "v"(b));
    return w;
}

// async global->LDS, 16B per lane. LDS dest is wave-uniform base + lane*16.
__device__ __forceinline__ void gld16(const void* g, void* l) {
    __builtin_amdgcn_global_load_lds((__attribute__((address_space(1))) void*)g,
                                     (__attribute__((address_space(3))) void*)l,
                                     16, 0, 0);
}

// ---------------- transpose + convert: in fp32 [R][C] -> out bf16 [C][R] ----------------
__global__ __launch_bounds__(256) void tcvt_kernel(const float* __restrict__ in,
                                                   short* __restrict__ out,
                                                   int R, int C) {
    __shared__ short tile[64][65];
    const int c0 = blockIdx.x * 64, r0 = blockIdx.y * 64;
    const int tr = threadIdx.x >> 6;   // 0..3
    const int tc = threadIdx.x & 63;
#pragma unroll
    for (int i = 0; i < 16; ++i) {
        int r = i * 4 + tr;
        tile[tc][r] = f2bf(in[(size_t)(r0 + r) * C + c0 + tc]);
    }
    __syncthreads();
#pragma unroll
    for (int i = 0; i < 16; ++i) {
        int c = i * 4 + tr;
        out[(size_t)(c0 + c) * R + r0 + tc] = tile[c][tc];
    }
}

// pack Wq/Wk/Wv (H,E,D) -> bf16 W^T layout [3072][1024]. K block pre-scaled by
// log2(e) so attention softmax can run in exp2 domain (exact weight fold).
__global__ __launch_bounds__(256) void pack_qkv_t(const float* __restrict__ Wq,
                                                  const float* __restrict__ Wk,
                                                  const float* __restrict__ Wv,
                                                  short* __restrict__ out) {
    __shared__ short tile[64][65];
    const int m = blockIdx.y;            // 0..47
    const int which = m >> 4, head = m & 15;
    const float* src = ((which == 0) ? Wq : (which == 1) ? Wk : Wv) + (size_t)head * EE * DD;
    const float scale = (which == 1) ? 1.44269504f : 1.0f;
    const int e0 = blockIdx.x * 64;
    const int tr = threadIdx.x >> 6, tc = threadIdx.x & 63;
#pragma unroll
    for (int i = 0; i < 16; ++i) {
        int e = i * 4 + tr;
        tile[tc][e] = f2bf(src[(size_t)(e0 + e) * DD + tc] * scale);
    }
    __syncthreads();
#pragma unroll
    for (int i = 0; i < 16; ++i) {
        int d = i * 4 + tr;
        out[(size_t)(which * 1024 + head * 64 + d) * EE + e0 + tc] = tile[d][tc];
    }
}

// ---------------- V transpose: qkv V-part [b*T+t][2048 + c] -> vT[(b*1024+c)][t] ----------------
__global__ __launch_bounds__(256) void vtr_kernel(const short* __restrict__ qkv,
                                                  short* __restrict__ vT) {
    __shared__ short tile[64][68];
    const int b = blockIdx.z;
    const int t0 = blockIdx.x * 64, c0 = blockIdx.y * 64;
    const int tr = threadIdx.x >> 4;          // 0..15
    const int q4 = (threadIdx.x & 15) * 4;    // 0..60
#pragma unroll
    for (int i = 0; i < 4; ++i) {
        int t = i * 16 + tr;
        short4v v = *(const short4v*)&qkv[((size_t)b * TT + t0 + t) * NQKV + 2048 + c0 + q4];
        *(short4v*)&tile[t][q4] = v;
    }
    __syncthreads();
#pragma unroll
    for (int i = 0; i < 4; ++i) {
        int c = i * 16 + tr;
        short4v v;
        v[0] = tile[q4 + 0][c];
        v[1] = tile[q4 + 1][c];
        v[2] = tile[q4 + 2][c];
        v[3] = tile[q4 + 3][c];
        *(short4v*)&vT[((size_t)b * 1024 + c0 + c) * TT + t0 + q4] = v;
    }
}

// ---------------- LayerNorm (fp32 in -> bf16 out) ----------------
__global__ __launch_bounds__(256) void ln_kernel(const float* __restrict__ x,
                                                 const float* __restrict__ g,
                                                 const float* __restrict__ b,
                                                 short* __restrict__ out) {
    __shared__ float red[4];
    const int row = blockIdx.x;
    const int tid = threadIdx.x;
    float4 v = *(const float4*)&x[(size_t)row * EE + tid * 4];
    float s = v.x + v.y + v.z + v.w;
#pragma unroll
    for (int off = 32; off >= 1; off >>= 1) s += __shfl_xor(s, off, 64);
    if ((tid & 63) == 0) red[tid >> 6] = s;
    __syncthreads();
    float mean = (red[0] + red[1] + red[2] + red[3]) * (1.0f / EE);
    __syncthreads();
    float d0 = v.x - mean, d1 = v.y - mean, d2 = v.z - mean, d3 = v.w - mean;
    s = d0 * d0 + d1 * d1 + d2 * d2 + d3 * d3;
#pragma unroll
    for (int off = 32; off >= 1; off >>= 1) s += __shfl_xor(s, off, 64);
    if ((tid & 63) == 0) red[tid >> 6] = s;
    __syncthreads();
    float var = (red[0] + red[1] + red[2] + red[3]) * (1.0f / EE);
    float rstd = rsqrtf(var + 1e-5f);
    int c = tid * 4;
    short4v o;
    o[0] = f2bf(d0 * rstd * g[c + 0] + b[c + 0]);
    o[1] = f2bf(d1 * rstd * g[c + 1] + b[c + 1]);
    o[2] = f2bf(d2 * rstd * g[c + 2] + b[c + 2]);
    o[3] = f2bf(d3 * rstd * g[c + 3] + b[c + 3]);
    *(short4v*)&out[(size_t)row * EE + c] = o;
}

// ---------------- bf16 GEMM: C[M,N] = A[M,K] @ B[K,N], Bt = B^T [N][K] ----------------
template <int BN, bool DBUF, bool HAS_BIAS, bool RELU, bool RESID, bool OUT_BF16>
__global__ __launch_bounds__(256) void gemm_bt(const short* __restrict__ A,
                                               const short* __restrict__ Bt,
                                               const float* __restrict__ bias,
                                               const float* __restrict__ resid,
                                               void* __restrict__ outp,
                                               int M, int N, int K) {
    constexpr int WRC = (BN == 128) ? 2 : 4;
    constexpr int WCC = (BN == 128) ? 2 : 1;
    constexpr int MI = 8 / WRC;
    constexpr int NI = BN / (16 * WCC);
    constexpr int BCH = BN / 32;
    constexpr int ASZ = 128 * 64, BSZ = BN * 64;

    __shared__ __align__(16) short As[(DBUF ? 2 : 1) * ASZ];
    __shared__ __align__(16) short Bs[(DBUF ? 2 : 1) * BSZ];

    const int tid = threadIdx.x;
    const int lane = tid & 63;
    const int wid = tid >> 6;
    const int wr = (WRC == 2) ? (wid >> 1) : wid;
    const int wc = (WCC == 2) ? (wid & 1) : 0;
    const int l15 = lane & 15, lhi = lane >> 4;

    // T1: XCD-aware bijective remap (all grids divisible by 8)
    int wg = blockIdx.y * gridDim.x + blockIdx.x;
    const int chunk = (gridDim.x * gridDim.y) >> 3;
    wg = (wg & 7) * chunk + (wg >> 3);
    const int bx = wg % gridDim.x;
    const int by = wg / gridDim.x;
    const int row0 = by * 128, col0 = bx * BN;

    const int srow = tid >> 3;                            // 0..31
    const int scol = (((tid & 7) ^ (srow & 7)) << 3);     // swizzled source col
    const int rsw = l15 & 7;                              // read-side swizzle key

    const int wrow0 = wr * (16 * MI);
    const int wcol0 = wc * (16 * NI);

    f32x4 acc[MI][NI] = {};

    auto stage = [&](int k0, int bs) {
#pragma unroll
        for (int ch = 0; ch < 4; ++ch)
            gld16(&A[(size_t)(row0 + ch * 32 + srow) * K + k0 + scol],
                  &As[bs * ASZ + ch * 2048 + wid * 512]);
#pragma unroll
        for (int ch = 0; ch < BCH; ++ch)
            gld16(&Bt[(size_t)(col0 + ch * 32 + srow) * K + k0 + scol],
                  &Bs[bs * BSZ + ch * 2048 + wid * 512]);
    };
    auto compute = [&](int bs) {
#pragma unroll
        for (int ks = 0; ks < 2; ++ks) {
            short8 af[MI], bf[NI];
#pragma unroll
            for (int mi = 0; mi < MI; ++mi)
                af[mi] = *(const short8*)&As[bs * ASZ + (wrow0 + mi * 16 + l15) * 64 +
                                             (((ks << 2) + lhi) ^ rsw) * 8];
#pragma unroll
            for (int ni = 0; ni < NI; ++ni)
                bf[ni] = *(const short8*)&Bs[bs * BSZ + (wcol0 + ni * 16 + l15) * 64 +
                                             (((ks << 2) + lhi) ^ rsw) * 8];
#pragma unroll
            for (int mi = 0; mi < MI; ++mi)
#pragma unroll
                for (int ni = 0; ni < NI; ++ni)
                    acc[mi][ni] = __builtin_amdgcn_mfma_f32_16x16x32_bf16(
                        af[mi], bf[ni], acc[mi][ni], 0, 0, 0);
        }
    };

    if (DBUF) {
        stage(0, 0);
        __syncthreads();
        int cur = 0;
        for (int k0 = 0; k0 < K; k0 += 64) {
            if (k0 + 64 < K) stage(k0 + 64, cur ^ 1);
            compute(cur);
            __syncthreads();
            cur ^= 1;
        }
    } else {
        for (int k0 = 0; k0 < K; k0 += 64) {
            __syncthreads();
            stage(k0, 0);
            __syncthreads();
            compute(0);
        }
    }

    float* outf = (float*)outp;
    short* outb = (short*)outp;
#pragma unroll
    for (int mi = 0; mi < MI; ++mi)
#pragma unroll
        for (int ni = 0; ni < NI; ++ni)
#pragma unroll
            for (int r = 0; r < 4; ++r) {
                int row = row0 + wrow0 + mi * 16 + lhi * 4 + r;
                int col = col0 + wcol0 + ni * 16 + l15;
                float v = acc[mi][ni][r];
                if (HAS_BIAS) v += bias[col];
                if (RELU) v = fmaxf(v, 0.f);
                if (RESID) v += resid[(size_t)row * N + col];
                if (OUT_BF16) outb[(size_t)row * N + col] = f2bf(v);
                else outf[(size_t)row * N + col] = v;
            }
}

// ---------------- flash attention: swapped QK^T, in-lane softmax (T12-style) ----------------
// 4 waves x 32 q-rows (2 groups of 16), KVBLK=64, dbuf K/V with slot swizzle.
// QK^T computed as mfma(K,Q) -> S^T: lane owns q=l15, kvs {nt*16+lhi*4+r}.
// kv-reduction = in-lane tree + 2 shfl_xor. P packed via v_cvt_pk_bf16_f32
// into Pl (u32 words, word idx = kv/2) and read back as PV A-fragments.
// Softmax in exp2 domain (Wk pre-scaled by log2 e). Defer-max THR = 11.5.
__global__ __launch_bounds__(256) void attn_kernel(const short* __restrict__ qkv,
                                                   const short* __restrict__ vT,
                                                   short* __restrict__ obuf) {
    __shared__ __align__(16) short Ks[2][64 * 64];
    __shared__ __align__(16) short Vs[2][64 * 64];
    __shared__ __align__(16) unsigned int Pl[4][2][16][40];   // [wave][g][q][kv/2 words+pad]
    const int tid = threadIdx.x;
    const int lane = tid & 63;
    const int wid = tid >> 6;
    const int l15 = lane & 15, lhi = lane >> 4;
    const int lhi4 = lhi * 4;

    // T1: XCD swizzle; 8 q-blocks per (b,h) stay on one XCD
    const int nb = ((blockIdx.x & 7) << 6) + (blockIdx.x >> 3);
    const int b = nb >> 7;
    const int h = (nb >> 3) & 15;
    const int q0 = (nb & 7) << 7;     // *128
    const size_t rbase = (size_t)b * TT;
    const int hq = h * 64;
    const short* vg = vT + ((size_t)b * 1024 + hq) * TT;

    const int srow = tid >> 3;                      // 0..31
    const int scol = (((tid & 7) ^ (srow & 7)) << 3);
    const int rsw = (l15 & 7);

    short8 aq[2][2];
#pragma unroll
    for (int g = 0; g < 2; ++g)
#pragma unroll
        for (int ks = 0; ks < 2; ++ks)
            aq[g][ks] = *(const short8*)&qkv[(rbase + q0 + wid * 32 + g * 16 + l15) * NQKV +
                                             hq + ks * 32 + lhi * 8];

    float mrun[2] = {-INFINITY, -INFINITY};
    float lsum[2] = {0.f, 0.f};
    f32x4 o[2][4] = {};

#pragma unroll
    for (int ch = 0; ch < 2; ++ch) {
        gld16(&qkv[(rbase + 0 + ch * 32 + srow) * NQKV + 1024 + hq + scol],
              &Ks[0][ch * 2048 + wid * 512]);
        gld16(&vg[(size_t)(ch * 32 + srow) * TT + 0 + scol],
              &Vs[0][ch * 2048 + wid * 512]);
    }
    __syncthreads();

    int cur = 0;
    for (int st = 0; st < TT; st += 64) {
        if (st + 64 < TT) {
#pragma unroll
            for (int ch = 0; ch < 2; ++ch) {
                gld16(&qkv[(rbase + st + 64 + ch * 32 + srow) * NQKV + 1024 + hq + scol],
                      &Ks[cur ^ 1][ch * 2048 + wid * 512]);
                gld16(&vg[(size_t)(ch * 32 + srow) * TT + st + 64 + scol],
                      &Vs[cur ^ 1][ch * 2048 + wid * 512]);
            }
        }
        const short* K = &Ks[cur][0];
        const short* V = &Vs[cur][0];

        // K fragments once per tile (shared by both q-groups)
        short8 kf[4][2];
#pragma unroll
        for (int nt = 0; nt < 4; ++nt)
#pragma unroll
            for (int ks = 0; ks < 2; ++ks)
                kf[nt][ks] = *(const short8*)&K[(nt * 16 + l15) * 64 +
                                               (((ks << 2) + lhi) ^ rsw) * 8];

        short8 pa[2][2];
#pragma unroll
        for (int g = 0; g < 2; ++g) {
            // S^T = K·Q^T : lane owns q=l15, kv = nt*16 + lhi*4 + r
            f32x4 stv[4] = {};
#pragma unroll
            for (int nt = 0; nt < 4; ++nt)
#pragma unroll
                for (int ks = 0; ks < 2; ++ks)
                    stv[nt] = __builtin_amdgcn_mfma_f32_16x16x32_bf16(
                        kf[nt][ks], aq[g][ks], stv[nt], 0, 0, 0);
            // in-lane tile max (16 values), then reduce across the 4 dup lanes
            float tn[4];
#pragma unroll
            for (int nt = 0; nt < 4; ++nt)
                tn[nt] = fmaxf(fmaxf(stv[nt][0], stv[nt][1]),
                               fmaxf(stv[nt][2], stv[nt][3]));
            float tm = fmaxf(fmaxf(tn[0], tn[1]), fmaxf(tn[2], tn[3]));
            tm = fmaxf(tm, __shfl_xor(tm, 16, 64));
            tm = fmaxf(tm, __shfl_xor(tm, 32, 64));
            // defer-max (exp2 domain: 8 nats = 11.54)
            const bool full = !__all(tm - mrun[g] <= 11.5f);
            if (full) {
                float mnew = fmaxf(mrun[g], tm);
                float fac = exp2f(mrun[g] - mnew);
                mrun[g] = mnew;
                lsum[g] *= fac;
                float f0 = __shfl(fac, lhi4 + 0, 64);
                float f1 = __shfl(fac, lhi4 + 1, 64);
                float f2 = __shfl(fac, lhi4 + 2, 64);
                float f3 = __shfl(fac, lhi4 + 3, 64);
#pragma unroll
                for (int dt = 0; dt < 4; ++dt) {
                    o[g][dt][0] *= f0; o[g][dt][1] *= f1;
                    o[g][dt][2] *= f2; o[g][dt][3] *= f3;
                }
            }
            // p = exp2(s - m), in-lane sum + 2 shfl
            float pv[4][4];
            float sn[4];
#pragma unroll
            for (int nt = 0; nt < 4; ++nt) {
#pragma unroll
                for (int r = 0; r < 4; ++r) pv[nt][r] = exp2f(stv[nt][r] - mrun[g]);
                sn[nt] = (pv[nt][0] + pv[nt][1]) + (pv[nt][2] + pv[nt][3]);
            }
            float rs = (sn[0] + sn[1]) + (sn[2] + sn[3]);
            rs += __shfl_xor(rs, 16, 64);
            rs += __shfl_xor(rs, 32, 64);
            lsum[g] += rs;
            // pack P^T into PV A-frag layout: word idx = kv/2 = nt*8 + lhi*2 + rp
#pragma unroll
            for (int nt = 0; nt < 4; ++nt) {
                uint2 ww;
                ww.x = cvtpk_bf16(pv[nt][0], pv[nt][1]);
                ww.y = cvtpk_bf16(pv[nt][2], pv[nt][3]);
                *(uint2*)&Pl[wid][g][l15][nt * 8 + lhi * 2] = ww;
            }
            pa[g][0] = *(const short8*)&Pl[wid][g][l15][lhi4];
            pa[g][1] = *(const short8*)&Pl[wid][g][l15][16 + lhi4];
        }

        // V fragments once per tile, then both PV updates
        short8 vf[4][2];
#pragma unroll
        for (int dt = 0; dt < 4; ++dt)
#pragma unroll
            for (int k2 = 0; k2 < 2; ++k2)
                vf[dt][k2] = *(const short8*)&V[(dt * 16 + l15) * 64 +
                                               (((k2 << 2) + lhi) ^ rsw) * 8];
#pragma unroll
        for (int g = 0; g < 2; ++g)
#pragma unroll
            for (int dt = 0; dt < 4; ++dt)
#pragma unroll
                for (int k2 = 0; k2 < 2; ++k2)
                    o[g][dt] = __builtin_amdgcn_mfma_f32_16x16x32_bf16(
                        pa[g][k2], vf[dt][k2], o[g][dt], 0, 0, 0);

        __syncthreads();
        cur ^= 1;
    }
#pragma unroll
    for (int g = 0; g < 2; ++g) {
        float inv = 1.0f / lsum[g];
        float i0 = __shfl(inv, lhi4 + 0, 64);
        float i1 = __shfl(inv, lhi4 + 1, 64);
        float i2 = __shfl(inv, lhi4 + 2, 64);
        float i3 = __shfl(inv, lhi4 + 3, 64);
#pragma unroll
        for (int dt = 0; dt < 4; ++dt) {
            int col = hq + dt * 16 + l15;
            size_t rw = rbase + q0 + wid * 32 + g * 16 + lhi4;
            obuf[(rw + 0) * EE + col] = f2bf(o[g][dt][0] * i0);
            obuf[(rw + 1) * EE + col] = f2bf(o[g][dt][1] * i1);
            obuf[(rw + 2) * EE + col] = f2bf(o[g][dt][2] * i2);
            obuf[(rw + 3) * EE + col] = f2bf(o[g][dt][3] * i3);
        }
    }
}

// ---------------- launch ----------------
extern "C" void kernel_launch(void* const* d_in, const int* in_sizes, int n_in,
                              void* d_out, int out_size, void* d_ws, size_t ws_size,
                              hipStream_t stream) {
    const float* x   = (const float*)d_in[0];
    const float* g1  = (const float*)d_in[1];
    const float* be1 = (const float*)d_in[2];
    const float* Wq  = (const float*)d_in[3];
    const float* Wk  = (const float*)d_in[4];
    const float* Wv  = (const float*)d_in[5];
    const float* Wp  = (const float*)d_in[6];
    const float* bp  = (const float*)d_in[7];
    const float* g2  = (const float*)d_in[8];
    const float* be2 = (const float*)d_in[9];
    const float* W1  = (const float*)d_in[10];
    const float* b1f = (const float*)d_in[11];
    const float* W2  = (const float*)d_in[12];
    const float* b2f = (const float*)d_in[13];

    char* p = (char*)d_ws;
    short* h_bf   = (short*)p; p += (size_t)MM * EE * 2;
    short* wqkv   = (short*)p; p += (size_t)EE * NQKV * 2;   // [3072][1024] W^T (K pre-scaled)
    short* qkv    = (short*)p; p += (size_t)MM * NQKV * 2;
    short* o_bf   = (short*)p; p += (size_t)MM * EE * 2;
    short* wp_bf  = (short*)p; p += (size_t)EE * EE * 2;     // [1024][1024] Wp^T
    float* x1     = (float*)p; p += (size_t)MM * EE * 4;
    short* h2_bf  = (short*)p; p += (size_t)MM * EE * 2;
    short* w1_bf  = (short*)p; p += (size_t)EE * E4 * 2;     // [4096][1024] W1^T
    short* mid_bf = (short*)p; p += (size_t)MM * E4 * 2;
    short* w2_bf  = (short*)p; p += (size_t)E4 * EE * 2;     // [1024][4096] W2^T
    short* vTb    = (short*)p; p += (size_t)BB * 1024 * TT * 2;  // [b][h*64+d][t]

    pack_qkv_t<<<dim3(16, 48), 256, 0, stream>>>(Wq, Wk, Wv, wqkv);
    tcvt_kernel<<<dim3(16, 16), 256, 0, stream>>>(Wp, wp_bf, EE, EE);
    tcvt_kernel<<<dim3(64, 16), 256, 0, stream>>>(W1, w1_bf, EE, E4);
    tcvt_kernel<<<dim3(16, 64), 256, 0, stream>>>(W2, w2_bf, E4, EE);

    ln_kernel<<<MM, 256, 0, stream>>>(x, g1, be1, h_bf);

    gemm_bt<128, false, false, false, false, true>
        <<<dim3(NQKV / 128, MM / 128), 256, 0, stream>>>(h_bf, wqkv, nullptr, nullptr,
                                                         qkv, MM, NQKV, EE);

    vtr_kernel<<<dim3(16, 16, BB), 256, 0, stream>>>(qkv, vTb);

    attn_kernel<<<BB * HH * (TT / 128), 256, 0, stream>>>(qkv, vTb, o_bf);

    gemm_bt<64, true, true, false, true, false>
        <<<dim3(EE / 64, MM / 128), 256, 0, stream>>>(o_bf, wp_bf, bp, x, x1, MM, EE, EE);

    ln_kernel<<<MM, 256, 0, stream>>>(x1, g2, be2, h2_bf);

    gemm_bt<128, false, true, true, false, true>
        <<<dim3(E4 / 128, MM / 128), 256, 0, stream>>>(h2_bf, w1_bf, b1f, nullptr,
                                                       mid_bf, MM, E4, EE);

    gemm_bt<64, true, true, false, true, false>
        <<<dim3(EE / 64, MM / 128), 256, 0, stream>>>(mid_bf, w2_bf, b2f, x1,
                                                      (float*)d_out, MM, EE, E4);
}

// Round 8
// 235.297 us; speedup vs baseline: 1.4850x; 1.0116x over previous
//
#include <hip/hip_runtime.h>
#include <hip/hip_bf16.h>

// Problem constants (B,T,E,H,D) = (4,1024,1024,16,64)
#define BB 4
#define TT 1024
#define EE 1024
#define HH 16
#define DD 64
#define MM 4096    // B*T rows
#define NQKV 3072  // q|k|v packed cols
#define E4 4096    // 4*E

using short8  = __attribute__((ext_vector_type(8))) short;
using short4v = __attribute__((ext_vector_type(4))) short;
using f32x4   = __attribute__((ext_vector_type(4))) float;

__device__ __forceinline__ short f2bf(float f) {
    __hip_bfloat16 h = __float2bfloat16(f);
    return *reinterpret_cast<short*>(&h);
}

// pack two f32 -> one u32 of 2 bf16 (low = a, high = b); no builtin on gfx950
__device__ __forceinline__ unsigned int cvtpk_bf16(float a, float b) {
    unsigned int w;
    asm("v_cvt_pk_bf16_f32 %0, %1, %2" : "=v"(w) : "v"(a), "v"(b));
    return w;
}

// async global->LDS, 16B per lane. LDS dest is wave-uniform base + lane*16.
__device__ __forceinline__ void gld16(const void* g, void* l) {
    __builtin_amdgcn_global_load_lds((__attribute__((address_space(1))) void*)g,
                                     (__attribute__((address_space(3))) void*)l,
                                     16, 0, 0);
}

// ---------------- transpose + convert: in fp32 [R][C] -> out bf16 [C][R] ----------------
__global__ __launch_bounds__(256) void tcvt_kernel(const float* __restrict__ in,
                                                   short* __restrict__ out,
                                                   int R, int C) {
    __shared__ short tile[64][65];
    const int c0 = blockIdx.x * 64, r0 = blockIdx.y * 64;
    const int tr = threadIdx.x >> 6;   // 0..3
    const int tc = threadIdx.x & 63;
#pragma unroll
    for (int i = 0; i < 16; ++i) {
        int r = i * 4 + tr;
        tile[tc][r] = f2bf(in[(size_t)(r0 + r) * C + c0 + tc]);
    }
    __syncthreads();
#pragma unroll
    for (int i = 0; i < 16; ++i) {
        int c = i * 4 + tr;
        out[(size_t)(c0 + c) * R + r0 + tc] = tile[c][tc];
    }
}

// pack Wq/Wk/Wv (H,E,D) -> bf16 W^T layout [3072][1024]. K block pre-scaled by
// log2(e) so attention softmax can run in exp2 domain (exact weight fold).
__global__ __launch_bounds__(256) void pack_qkv_t(const float* __restrict__ Wq,
                                                  const float* __restrict__ Wk,
                                                  const float* __restrict__ Wv,
                                                  short* __restrict__ out) {
    __shared__ short tile[64][65];
    const int m = blockIdx.y;            // 0..47
    const int which = m >> 4, head = m & 15;
    const float* src = ((which == 0) ? Wq : (which == 1) ? Wk : Wv) + (size_t)head * EE * DD;
    const float scale = (which == 1) ? 1.44269504f : 1.0f;
    const int e0 = blockIdx.x * 64;
    const int tr = threadIdx.x >> 6, tc = threadIdx.x & 63;
#pragma unroll
    for (int i = 0; i < 16; ++i) {
        int e = i * 4 + tr;
        tile[tc][e] = f2bf(src[(size_t)(e0 + e) * DD + tc] * scale);
    }
    __syncthreads();
#pragma unroll
    for (int i = 0; i < 16; ++i) {
        int d = i * 4 + tr;
        out[(size_t)(which * 1024 + head * 64 + d) * EE + e0 + tc] = tile[d][tc];
    }
}

// ---------------- V transpose: qkv V-part [b*T+t][2048 + c] -> vT[(b*1024+c)][t] ----------------
__global__ __launch_bounds__(256) void vtr_kernel(const short* __restrict__ qkv,
                                                  short* __restrict__ vT) {
    __shared__ short tile[64][68];
    const int b = blockIdx.z;
    const int t0 = blockIdx.x * 64, c0 = blockIdx.y * 64;
    const int tr = threadIdx.x >> 4;          // 0..15
    const int q4 = (threadIdx.x & 15) * 4;    // 0..60
#pragma unroll
    for (int i = 0; i < 4; ++i) {
        int t = i * 16 + tr;
        short4v v = *(const short4v*)&qkv[((size_t)b * TT + t0 + t) * NQKV + 2048 + c0 + q4];
        *(short4v*)&tile[t][q4] = v;
    }
    __syncthreads();
#pragma unroll
    for (int i = 0; i < 4; ++i) {
        int c = i * 16 + tr;
        short4v v;
        v[0] = tile[q4 + 0][c];
        v[1] = tile[q4 + 1][c];
        v[2] = tile[q4 + 2][c];
        v[3] = tile[q4 + 3][c];
        *(short4v*)&vT[((size_t)b * 1024 + c0 + c) * TT + t0 + q4] = v;
    }
}

// ---------------- LayerNorm (fp32 in -> bf16 out) ----------------
__global__ __launch_bounds__(256) void ln_kernel(const float* __restrict__ x,
                                                 const float* __restrict__ g,
                                                 const float* __restrict__ b,
                                                 short* __restrict__ out) {
    __shared__ float red[4];
    const int row = blockIdx.x;
    const int tid = threadIdx.x;
    float4 v = *(const float4*)&x[(size_t)row * EE + tid * 4];
    float s = v.x + v.y + v.z + v.w;
#pragma unroll
    for (int off = 32; off >= 1; off >>= 1) s += __shfl_xor(s, off, 64);
    if ((tid & 63) == 0) red[tid >> 6] = s;
    __syncthreads();
    float mean = (red[0] + red[1] + red[2] + red[3]) * (1.0f / EE);
    __syncthreads();
    float d0 = v.x - mean, d1 = v.y - mean, d2 = v.z - mean, d3 = v.w - mean;
    s = d0 * d0 + d1 * d1 + d2 * d2 + d3 * d3;
#pragma unroll
    for (int off = 32; off >= 1; off >>= 1) s += __shfl_xor(s, off, 64);
    if ((tid & 63) == 0) red[tid >> 6] = s;
    __syncthreads();
    float var = (red[0] + red[1] + red[2] + red[3]) * (1.0f / EE);
    float rstd = rsqrtf(var + 1e-5f);
    int c = tid * 4;
    short4v o;
    o[0] = f2bf(d0 * rstd * g[c + 0] + b[c + 0]);
    o[1] = f2bf(d1 * rstd * g[c + 1] + b[c + 1]);
    o[2] = f2bf(d2 * rstd * g[c + 2] + b[c + 2]);
    o[3] = f2bf(d3 * rstd * g[c + 3] + b[c + 3]);
    *(short4v*)&out[(size_t)row * EE + c] = o;
}

// ---------------- bf16 GEMM: C[M,N] = A[M,K] @ B[K,N], Bt = B^T [N][K] ----------------
// PIPE=0: single-buffer 2-phase (good when >=3 blocks/CU give cross-block overlap).
// PIPE=1: 2-deep counted-vmcnt pipeline (T3/T4): prologue stages tiles 0,1;
//   per iter: vmcnt(6) [next stage's 6 loads stay in flight] -> s_barrier ->
//   compute -> s_barrier -> stage(t+2) into just-read buffer. Never drains
//   vmcnt to 0 in the loop. For grid-capped shapes (2 blocks/CU).
template <int BN, int PIPE, bool HAS_BIAS, bool RELU, bool RESID, bool OUT_BF16>
__global__ __launch_bounds__(256) void gemm_bt(const short* __restrict__ A,
                                               const short* __restrict__ Bt,
                                               const float* __restrict__ bias,
                                               const float* __restrict__ resid,
                                               void* __restrict__ outp,
                                               int M, int N, int K) {
    constexpr int WRC = (BN == 128) ? 2 : 4;
    constexpr int WCC = (BN == 128) ? 2 : 1;
    constexpr int MI = 8 / WRC;
    constexpr int NI = BN / (16 * WCC);
    constexpr int BCH = BN / 32;
    constexpr int ASZ = 128 * 64, BSZ = BN * 64;

    __shared__ __align__(16) short As[(PIPE ? 2 : 1) * ASZ];
    __shared__ __align__(16) short Bs[(PIPE ? 2 : 1) * BSZ];

    const int tid = threadIdx.x;
    const int lane = tid & 63;
    const int wid = tid >> 6;
    const int wr = (WRC == 2) ? (wid >> 1) : wid;
    const int wc = (WCC == 2) ? (wid & 1) : 0;
    const int l15 = lane & 15, lhi = lane >> 4;

    // T1: XCD-aware bijective remap (all grids divisible by 8)
    int wg = blockIdx.y * gridDim.x + blockIdx.x;
    const int chunk = (gridDim.x * gridDim.y) >> 3;
    wg = (wg & 7) * chunk + (wg >> 3);
    const int bx = wg % gridDim.x;
    const int by = wg / gridDim.x;
    const int row0 = by * 128, col0 = bx * BN;

    const int srow = tid >> 3;                            // 0..31
    const int scol = (((tid & 7) ^ (srow & 7)) << 3);     // swizzled source col
    const int rsw = l15 & 7;                              // read-side swizzle key

    const int wrow0 = wr * (16 * MI);
    const int wcol0 = wc * (16 * NI);

    f32x4 acc[MI][NI] = {};

    auto stage = [&](int k0, int bs) {   // exactly 4 + BCH = 6 vmem insts/wave (BN=64)
#pragma unroll
        for (int ch = 0; ch < 4; ++ch)
            gld16(&A[(size_t)(row0 + ch * 32 + srow) * K + k0 + scol],
                  &As[bs * ASZ + ch * 2048 + wid * 512]);
#pragma unroll
        for (int ch = 0; ch < BCH; ++ch)
            gld16(&Bt[(size_t)(col0 + ch * 32 + srow) * K + k0 + scol],
                  &Bs[bs * BSZ + ch * 2048 + wid * 512]);
    };
    auto compute = [&](int bs) {
#pragma unroll
        for (int ks = 0; ks < 2; ++ks) {
            short8 af[MI], bf[NI];
#pragma unroll
            for (int mi = 0; mi < MI; ++mi)
                af[mi] = *(const short8*)&As[bs * ASZ + (wrow0 + mi * 16 + l15) * 64 +
                                             (((ks << 2) + lhi) ^ rsw) * 8];
#pragma unroll
            for (int ni = 0; ni < NI; ++ni)
                bf[ni] = *(const short8*)&Bs[bs * BSZ + (wcol0 + ni * 16 + l15) * 64 +
                                             (((ks << 2) + lhi) ^ rsw) * 8];
#pragma unroll
            for (int mi = 0; mi < MI; ++mi)
#pragma unroll
                for (int ni = 0; ni < NI; ++ni)
                    acc[mi][ni] = __builtin_amdgcn_mfma_f32_16x16x32_bf16(
                        af[mi], bf[ni], acc[mi][ni], 0, 0, 0);
        }
    };

    if (PIPE == 1) {
        const int nt = K >> 6;           // >= 2 for all our shapes
        stage(0, 0);
        stage(64, 1);
        int cur = 0;
        for (int t = 0; t < nt; ++t) {
            // wait: this wave's stage-t loads done; stage-(t+1)'s 6 stay in flight
            if (t + 1 < nt) asm volatile("s_waitcnt vmcnt(6)" ::: "memory");
            else            asm volatile("s_waitcnt vmcnt(0)" ::: "memory");
            __builtin_amdgcn_s_barrier();          // all waves' tile-t loads landed
            __builtin_amdgcn_sched_barrier(0);     // pin ds_reads below barrier
            compute(cur);
            __builtin_amdgcn_sched_barrier(0);     // pin ds_reads above barrier
            __builtin_amdgcn_s_barrier();          // all waves done reading buf[cur]
            if (t + 2 < nt) stage((t + 2) << 6, cur);
            cur ^= 1;
        }
    } else {
        for (int k0 = 0; k0 < K; k0 += 64) {
            __syncthreads();
            stage(k0, 0);
            __syncthreads();
            compute(0);
        }
    }

    float* outf = (float*)outp;
    short* outb = (short*)outp;
#pragma unroll
    for (int mi = 0; mi < MI; ++mi)
#pragma unroll
        for (int ni = 0; ni < NI; ++ni)
#pragma unroll
            for (int r = 0; r < 4; ++r) {
                int row = row0 + wrow0 + mi * 16 + lhi * 4 + r;
                int col = col0 + wcol0 + ni * 16 + l15;
                float v = acc[mi][ni][r];
                if (HAS_BIAS) v += bias[col];
                if (RELU) v = fmaxf(v, 0.f);
                if (RESID) v += resid[(size_t)row * N + col];
                if (OUT_BF16) outb[(size_t)row * N + col] = f2bf(v);
                else outf[(size_t)row * N + col] = v;
            }
}

// ---------------- flash attention: swapped QK^T, in-lane softmax (T12-style) ----------------
__global__ __launch_bounds__(256) void attn_kernel(const short* __restrict__ qkv,
                                                   const short* __restrict__ vT,
                                                   short* __restrict__ obuf) {
    __shared__ __align__(16) short Ks[2][64 * 64];
    __shared__ __align__(16) short Vs[2][64 * 64];
    __shared__ __align__(16) unsigned int Pl[4][2][16][40];   // [wave][g][q][kv/2 words+pad]
    const int tid = threadIdx.x;
    const int lane = tid & 63;
    const int wid = tid >> 6;
    const int l15 = lane & 15, lhi = lane >> 4;
    const int lhi4 = lhi * 4;

    // T1: XCD swizzle; 8 q-blocks per (b,h) stay on one XCD
    const int nb = ((blockIdx.x & 7) << 6) + (blockIdx.x >> 3);
    const int b = nb >> 7;
    const int h = (nb >> 3) & 15;
    const int q0 = (nb & 7) << 7;     // *128
    const size_t rbase = (size_t)b * TT;
    const int hq = h * 64;
    const short* vg = vT + ((size_t)b * 1024 + hq) * TT;

    const int srow = tid >> 3;                      // 0..31
    const int scol = (((tid & 7) ^ (srow & 7)) << 3);
    const int rsw = (l15 & 7);

    short8 aq[2][2];
#pragma unroll
    for (int g = 0; g < 2; ++g)
#pragma unroll
        for (int ks = 0; ks < 2; ++ks)
            aq[g][ks] = *(const short8*)&qkv[(rbase + q0 + wid * 32 + g * 16 + l15) * NQKV +
                                             hq + ks * 32 + lhi * 8];

    float mrun[2] = {-INFINITY, -INFINITY};
    float lsum[2] = {0.f, 0.f};
    f32x4 o[2][4] = {};

#pragma unroll
    for (int ch = 0; ch < 2; ++ch) {
        gld16(&qkv[(rbase + 0 + ch * 32 + srow) * NQKV + 1024 + hq + scol],
              &Ks[0][ch * 2048 + wid * 512]);
        gld16(&vg[(size_t)(ch * 32 + srow) * TT + 0 + scol],
              &Vs[0][ch * 2048 + wid * 512]);
    }
    __syncthreads();

    int cur = 0;
    for (int st = 0; st < TT; st += 64) {
        if (st + 64 < TT) {
#pragma unroll
            for (int ch = 0; ch < 2; ++ch) {
                gld16(&qkv[(rbase + st + 64 + ch * 32 + srow) * NQKV + 1024 + hq + scol],
                      &Ks[cur ^ 1][ch * 2048 + wid * 512]);
                gld16(&vg[(size_t)(ch * 32 + srow) * TT + st + 64 + scol],
                      &Vs[cur ^ 1][ch * 2048 + wid * 512]);
            }
        }
        const short* K = &Ks[cur][0];
        const short* V = &Vs[cur][0];

        // K fragments once per tile (shared by both q-groups)
        short8 kf[4][2];
#pragma unroll
        for (int nt = 0; nt < 4; ++nt)
#pragma unroll
            for (int ks = 0; ks < 2; ++ks)
                kf[nt][ks] = *(const short8*)&K[(nt * 16 + l15) * 64 +
                                               (((ks << 2) + lhi) ^ rsw) * 8];

        short8 pa[2][2];
#pragma unroll
        for (int g = 0; g < 2; ++g) {
            // S^T = K·Q^T : lane owns q=l15, kv = nt*16 + lhi*4 + r
            f32x4 stv[4] = {};
#pragma unroll
            for (int nt = 0; nt < 4; ++nt)
#pragma unroll
                for (int ks = 0; ks < 2; ++ks)
                    stv[nt] = __builtin_amdgcn_mfma_f32_16x16x32_bf16(
                        kf[nt][ks], aq[g][ks], stv[nt], 0, 0, 0);
            float tn[4];
#pragma unroll
            for (int nt = 0; nt < 4; ++nt)
                tn[nt] = fmaxf(fmaxf(stv[nt][0], stv[nt][1]),
                               fmaxf(stv[nt][2], stv[nt][3]));
            float tm = fmaxf(fmaxf(tn[0], tn[1]), fmaxf(tn[2], tn[3]));
            tm = fmaxf(tm, __shfl_xor(tm, 16, 64));
            tm = fmaxf(tm, __shfl_xor(tm, 32, 64));
            const bool full = !__all(tm - mrun[g] <= 11.5f);
            if (full) {
                float mnew = fmaxf(mrun[g], tm);
                float fac = exp2f(mrun[g] - mnew);
                mrun[g] = mnew;
                lsum[g] *= fac;
                float f0 = __shfl(fac, lhi4 + 0, 64);
                float f1 = __shfl(fac, lhi4 + 1, 64);
                float f2 = __shfl(fac, lhi4 + 2, 64);
                float f3 = __shfl(fac, lhi4 + 3, 64);
#pragma unroll
                for (int dt = 0; dt < 4; ++dt) {
                    o[g][dt][0] *= f0; o[g][dt][1] *= f1;
                    o[g][dt][2] *= f2; o[g][dt][3] *= f3;
                }
            }
            float pv[4][4];
            float sn[4];
#pragma unroll
            for (int nt = 0; nt < 4; ++nt) {
#pragma unroll
                for (int r = 0; r < 4; ++r) pv[nt][r] = exp2f(stv[nt][r] - mrun[g]);
                sn[nt] = (pv[nt][0] + pv[nt][1]) + (pv[nt][2] + pv[nt][3]);
            }
            float rs = (sn[0] + sn[1]) + (sn[2] + sn[3]);
            rs += __shfl_xor(rs, 16, 64);
            rs += __shfl_xor(rs, 32, 64);
            lsum[g] += rs;
#pragma unroll
            for (int nt = 0; nt < 4; ++nt) {
                uint2 ww;
                ww.x = cvtpk_bf16(pv[nt][0], pv[nt][1]);
                ww.y = cvtpk_bf16(pv[nt][2], pv[nt][3]);
                *(uint2*)&Pl[wid][g][l15][nt * 8 + lhi * 2] = ww;
            }
            pa[g][0] = *(const short8*)&Pl[wid][g][l15][lhi4];
            pa[g][1] = *(const short8*)&Pl[wid][g][l15][16 + lhi4];
        }

        short8 vf[4][2];
#pragma unroll
        for (int dt = 0; dt < 4; ++dt)
#pragma unroll
            for (int k2 = 0; k2 < 2; ++k2)
                vf[dt][k2] = *(const short8*)&V[(dt * 16 + l15) * 64 +
                                               (((k2 << 2) + lhi) ^ rsw) * 8];
#pragma unroll
        for (int g = 0; g < 2; ++g)
#pragma unroll
            for (int dt = 0; dt < 4; ++dt)
#pragma unroll
                for (int k2 = 0; k2 < 2; ++k2)
                    o[g][dt] = __builtin_amdgcn_mfma_f32_16x16x32_bf16(
                        pa[g][k2], vf[dt][k2], o[g][dt], 0, 0, 0);

        __syncthreads();
        cur ^= 1;
    }
#pragma unroll
    for (int g = 0; g < 2; ++g) {
        float inv = 1.0f / lsum[g];
        float i0 = __shfl(inv, lhi4 + 0, 64);
        float i1 = __shfl(inv, lhi4 + 1, 64);
        float i2 = __shfl(inv, lhi4 + 2, 64);
        float i3 = __shfl(inv, lhi4 + 3, 64);
#pragma unroll
        for (int dt = 0; dt < 4; ++dt) {
            int col = hq + dt * 16 + l15;
            size_t rw = rbase + q0 + wid * 32 + g * 16 + lhi4;
            obuf[(rw + 0) * EE + col] = f2bf(o[g][dt][0] * i0);
            obuf[(rw + 1) * EE + col] = f2bf(o[g][dt][1] * i1);
            obuf[(rw + 2) * EE + col] = f2bf(o[g][dt][2] * i2);
            obuf[(rw + 3) * EE + col] = f2bf(o[g][dt][3] * i3);
        }
    }
}

// ---------------- launch ----------------
extern "C" void kernel_launch(void* const* d_in, const int* in_sizes, int n_in,
                              void* d_out, int out_size, void* d_ws, size_t ws_size,
                              hipStream_t stream) {
    const float* x   = (const float*)d_in[0];
    const float* g1  = (const float*)d_in[1];
    const float* be1 = (const float*)d_in[2];
    const float* Wq  = (const float*)d_in[3];
    const float* Wk  = (const float*)d_in[4];
    const float* Wv  = (const float*)d_in[5];
    const float* Wp  = (const float*)d_in[6];
    const float* bp  = (const float*)d_in[7];
    const float* g2  = (const float*)d_in[8];
    const float* be2 = (const float*)d_in[9];
    const float* W1  = (const float*)d_in[10];
    const float* b1f = (const float*)d_in[11];
    const float* W2  = (const float*)d_in[12];
    const float* b2f = (const float*)d_in[13];

    char* p = (char*)d_ws;
    short* h_bf   = (short*)p; p += (size_t)MM * EE * 2;
    short* wqkv   = (short*)p; p += (size_t)EE * NQKV * 2;   // [3072][1024] W^T (K pre-scaled)
    short* qkv    = (short*)p; p += (size_t)MM * NQKV * 2;
    short* o_bf   = (short*)p; p += (size_t)MM * EE * 2;
    short* wp_bf  = (short*)p; p += (size_t)EE * EE * 2;     // [1024][1024] Wp^T
    float* x1     = (float*)p; p += (size_t)MM * EE * 4;
    short* h2_bf  = (short*)p; p += (size_t)MM * EE * 2;
    short* w1_bf  = (short*)p; p += (size_t)EE * E4 * 2;     // [4096][1024] W1^T
    short* mid_bf = (short*)p; p += (size_t)MM * E4 * 2;
    short* w2_bf  = (short*)p; p += (size_t)E4 * EE * 2;     // [1024][4096] W2^T
    short* vTb    = (short*)p; p += (size_t)BB * 1024 * TT * 2;  // [b][h*64+d][t]

    pack_qkv_t<<<dim3(16, 48), 256, 0, stream>>>(Wq, Wk, Wv, wqkv);
    tcvt_kernel<<<dim3(16, 16), 256, 0, stream>>>(Wp, wp_bf, EE, EE);
    tcvt_kernel<<<dim3(64, 16), 256, 0, stream>>>(W1, w1_bf, EE, E4);
    tcvt_kernel<<<dim3(16, 64), 256, 0, stream>>>(W2, w2_bf, E4, EE);

    ln_kernel<<<MM, 256, 0, stream>>>(x, g1, be1, h_bf);

    gemm_bt<128, 0, false, false, false, true>
        <<<dim3(NQKV / 128, MM / 128), 256, 0, stream>>>(h_bf, wqkv, nullptr, nullptr,
                                                         qkv, MM, NQKV, EE);

    vtr_kernel<<<dim3(16, 16, BB), 256, 0, stream>>>(qkv, vTb);

    attn_kernel<<<BB * HH * (TT / 128), 256, 0, stream>>>(qkv, vTb, o_bf);

    gemm_bt<64, 1, true, false, true, false>
        <<<dim3(EE / 64, MM / 128), 256, 0, stream>>>(o_bf, wp_bf, bp, x, x1, MM, EE, EE);

    ln_kernel<<<MM, 256, 0, stream>>>(x1, g2, be2, h2_bf);

    gemm_bt<128, 0, true, true, false, true>
        <<<dim3(E4 / 128, MM / 128), 256, 0, stream>>>(h2_bf, w1_bf, b1f, nullptr,
                                                       mid_bf, MM, E4, EE);

    gemm_bt<64, 1, true, false, true, false>
        <<<dim3(EE / 64, MM / 128), 256, 0, stream>>>(mid_bf, w2_bf, b2f, x1,
                                                      (float*)d_out, MM, EE, E4);
}

// Round 9
// 221.302 us; speedup vs baseline: 1.5789x; 1.0632x over previous
//
#include <hip/hip_runtime.h>
#include <hip/hip_bf16.h>

// Problem constants (B,T,E,H,D) = (4,1024,1024,16,64)
#define BB 4
#define TT 1024
#define EE 1024
#define HH 16
#define DD 64
#define MM 4096    // B*T rows
#define NQKV 3072  // q|k|v packed cols
#define E4 4096    // 4*E

using short8  = __attribute__((ext_vector_type(8))) short;
using short4v = __attribute__((ext_vector_type(4))) short;
using f32x4   = __attribute__((ext_vector_type(4))) float;

__device__ __forceinline__ short f2bf(float f) {
    __hip_bfloat16 h = __float2bfloat16(f);
    return *reinterpret_cast<short*>(&h);
}

// pack two f32 -> one u32 of 2 bf16 (low = a, high = b); no builtin on gfx950
__device__ __forceinline__ unsigned int cvtpk_bf16(float a, float b) {
    unsigned int w;
    asm("v_cvt_pk_bf16_f32 %0, %1, %2" : "=v"(w) : "v"(a), "v"(b));
    return w;
}

// async global->LDS, 16B per lane. LDS dest is wave-uniform base + lane*16.
__device__ __forceinline__ void gld16(const void* g, void* l) {
    __builtin_amdgcn_global_load_lds((__attribute__((address_space(1))) void*)g,
                                     (__attribute__((address_space(3))) void*)l,
                                     16, 0, 0);
}

// ---------------- transpose + convert: in fp32 [R][C] -> out bf16 [C][R] ----------------
__global__ __launch_bounds__(256) void tcvt_kernel(const float* __restrict__ in,
                                                   short* __restrict__ out,
                                                   int R, int C) {
    __shared__ short tile[64][65];
    const int c0 = blockIdx.x * 64, r0 = blockIdx.y * 64;
    const int tr = threadIdx.x >> 6;   // 0..3
    const int tc = threadIdx.x & 63;
#pragma unroll
    for (int i = 0; i < 16; ++i) {
        int r = i * 4 + tr;
        tile[tc][r] = f2bf(in[(size_t)(r0 + r) * C + c0 + tc]);
    }
    __syncthreads();
#pragma unroll
    for (int i = 0; i < 16; ++i) {
        int c = i * 4 + tr;
        out[(size_t)(c0 + c) * R + r0 + tc] = tile[c][tc];
    }
}

// pack Wq/Wk/Wv (H,E,D) -> bf16 W^T layout [3072][1024]. K block pre-scaled by
// log2(e) so attention softmax can run in exp2 domain (exact weight fold).
__global__ __launch_bounds__(256) void pack_qkv_t(const float* __restrict__ Wq,
                                                  const float* __restrict__ Wk,
                                                  const float* __restrict__ Wv,
                                                  short* __restrict__ out) {
    __shared__ short tile[64][65];
    const int m = blockIdx.y;            // 0..47
    const int which = m >> 4, head = m & 15;
    const float* src = ((which == 0) ? Wq : (which == 1) ? Wk : Wv) + (size_t)head * EE * DD;
    const float scale = (which == 1) ? 1.44269504f : 1.0f;
    const int e0 = blockIdx.x * 64;
    const int tr = threadIdx.x >> 6, tc = threadIdx.x & 63;
#pragma unroll
    for (int i = 0; i < 16; ++i) {
        int e = i * 4 + tr;
        tile[tc][e] = f2bf(src[(size_t)(e0 + e) * DD + tc] * scale);
    }
    __syncthreads();
#pragma unroll
    for (int i = 0; i < 16; ++i) {
        int d = i * 4 + tr;
        out[(size_t)(which * 1024 + head * 64 + d) * EE + e0 + tc] = tile[d][tc];
    }
}

// ---------------- V transpose: qkv V-part [b*T+t][2048 + c] -> vT[(b*1024+c)][t] ----------------
__global__ __launch_bounds__(256) void vtr_kernel(const short* __restrict__ qkv,
                                                  short* __restrict__ vT) {
    __shared__ short tile[64][68];
    const int b = blockIdx.z;
    const int t0 = blockIdx.x * 64, c0 = blockIdx.y * 64;
    const int tr = threadIdx.x >> 4;          // 0..15
    const int q4 = (threadIdx.x & 15) * 4;    // 0..60
#pragma unroll
    for (int i = 0; i < 4; ++i) {
        int t = i * 16 + tr;
        short4v v = *(const short4v*)&qkv[((size_t)b * TT + t0 + t) * NQKV + 2048 + c0 + q4];
        *(short4v*)&tile[t][q4] = v;
    }
    __syncthreads();
#pragma unroll
    for (int i = 0; i < 4; ++i) {
        int c = i * 16 + tr;
        short4v v;
        v[0] = tile[q4 + 0][c];
        v[1] = tile[q4 + 1][c];
        v[2] = tile[q4 + 2][c];
        v[3] = tile[q4 + 3][c];
        *(short4v*)&vT[((size_t)b * 1024 + c0 + c) * TT + t0 + q4] = v;
    }
}

// ---------------- LayerNorm (fp32 in -> bf16 out) ----------------
__global__ __launch_bounds__(256) void ln_kernel(const float* __restrict__ x,
                                                 const float* __restrict__ g,
                                                 const float* __restrict__ b,
                                                 short* __restrict__ out) {
    __shared__ float red[4];
    const int row = blockIdx.x;
    const int tid = threadIdx.x;
    float4 v = *(const float4*)&x[(size_t)row * EE + tid * 4];
    float s = v.x + v.y + v.z + v.w;
#pragma unroll
    for (int off = 32; off >= 1; off >>= 1) s += __shfl_xor(s, off, 64);
    if ((tid & 63) == 0) red[tid >> 6] = s;
    __syncthreads();
    float mean = (red[0] + red[1] + red[2] + red[3]) * (1.0f / EE);
    __syncthreads();
    float d0 = v.x - mean, d1 = v.y - mean, d2 = v.z - mean, d3 = v.w - mean;
    s = d0 * d0 + d1 * d1 + d2 * d2 + d3 * d3;
#pragma unroll
    for (int off = 32; off >= 1; off >>= 1) s += __shfl_xor(s, off, 64);
    if ((tid & 63) == 0) red[tid >> 6] = s;
    __syncthreads();
    float var = (red[0] + red[1] + red[2] + red[3]) * (1.0f / EE);
    float rstd = rsqrtf(var + 1e-5f);
    int c = tid * 4;
    short4v o;
    o[0] = f2bf(d0 * rstd * g[c + 0] + b[c + 0]);
    o[1] = f2bf(d1 * rstd * g[c + 1] + b[c + 1]);
    o[2] = f2bf(d2 * rstd * g[c + 2] + b[c + 2]);
    o[3] = f2bf(d3 * rstd * g[c + 3] + b[c + 3]);
    *(short4v*)&out[(size_t)row * EE + c] = o;
}

// ---------------- 256x256 8-phase bf16 GEMM (T2+T3+T4+T5), out bf16 ----------------
// C[M,N] = A[M,K] @ Bt^T, Bt = B^T [N][K]. 512 thr = 8 waves (2M x 4N), BK=64,
// per-wave C = 128x64 (acc[8][4]), 16 MFMA per phase, 4 phases per K-tile.
// LDS: 2 buf x (A 2x[128][64] + B 2x[128][64]) = 128 KB. Slot swizzle: source
// k-slot ^= row&7 (LDS linear for global_load_lds), ds_read slot ^= l15&7.
// Staging schedule (tile u, buf=u&1): p0/p1 stage (u+1).A half0/1 -> buf^1
// (freed: tile u-1 reads done at its p3 + barrier); p2/p3 stage (u+2).B
// half0/1 -> buf (tile u's B read only in p0, + closing barriers between).
// vmcnt(4) at each tile's p3 (before closing barrier = publication barrier):
// leaves (u+2).B's 4 loads in flight; never drains in steady state.
// Prologue: t0.A, t0.B, t1.B (12 loads) then vmcnt(4) + barrier.
template <bool HAS_BIAS, bool RELU>
__global__ __launch_bounds__(512, 2) void gemm256(const short* __restrict__ A,
                                                  const short* __restrict__ Bt,
                                                  const float* __restrict__ bias,
                                                  short* __restrict__ out,
                                                  int M, int N, int K) {
    __shared__ __align__(16) short Ab[2][2][8192];   // [buf][half][128*64]
    __shared__ __align__(16) short Bb[2][2][8192];

    const int tid = threadIdx.x;
    const int lane = tid & 63;
    const int wid = tid >> 6;          // 0..7
    const int wr = wid >> 2;           // 0..1  (M half)
    const int wc = wid & 3;            // 0..3  (N quarter)
    const int l15 = lane & 15, lhi = lane >> 4;
    const int rsw = l15 & 7;

    // T1: XCD-aware bijective remap (grids 192/256, both %8==0)
    int wg = blockIdx.y * gridDim.x + blockIdx.x;
    const int chunk = (gridDim.x * gridDim.y) >> 3;
    wg = (wg & 7) * chunk + (wg >> 3);
    const int bx = wg % gridDim.x, by = wg / gridDim.x;
    const int row0 = by * 256, col0 = bx * 256;

    const int srow = tid >> 3;                         // 0..63
    const int scol = (((tid & 7) ^ (srow & 7)) << 3);  // pre-swizzled k-offset

    const int NT = K >> 6;

    f32x4 acc[8][4] = {};

    auto stageA = [&](int b, int h, int k0) {   // one half-tile = 2 gld16/thread
#pragma unroll
        for (int j = 0; j < 2; ++j)
            gld16(&A[(size_t)(row0 + h * 128 + j * 64 + srow) * K + k0 + scol],
                  &Ab[b][h][j * 4096 + wid * 512]);
    };
    auto stageB = [&](int b, int h, int k0) {
#pragma unroll
        for (int j = 0; j < 2; ++j)
            gld16(&Bt[(size_t)(col0 + h * 128 + j * 64 + srow) * K + k0 + scol],
                  &Bb[b][h][j * 4096 + wid * 512]);
    };

    // prologue: t0.A, t0.B, t1.B
    stageA(0, 0, 0); stageA(0, 1, 0);
    stageB(0, 0, 0); stageB(0, 1, 0);
    if (NT > 1) {
        stageB(1, 0, 64); stageB(1, 1, 64);
        asm volatile("s_waitcnt vmcnt(4)" ::: "memory");
    } else {
        asm volatile("s_waitcnt vmcnt(0)" ::: "memory");
    }
    __builtin_amdgcn_s_barrier();   // publication of t0

    for (int u = 0; u < NT; ++u) {
        const int buf = u & 1;
        short8 bfr[4][2];
#pragma unroll
        for (int p = 0; p < 4; ++p) {
            if (p == 0) {
#pragma unroll
                for (int n = 0; n < 4; ++n)
#pragma unroll
                    for (int ks = 0; ks < 2; ++ks)
                        bfr[n][ks] = *(const short8*)&Bb[buf][wc >> 1]
                            [((wc & 1) * 64 + n * 16 + l15) * 64 +
                             (((ks << 2) + lhi) ^ rsw) * 8];
            }
            short8 af[2][2];
#pragma unroll
            for (int mi = 0; mi < 2; ++mi)
#pragma unroll
                for (int ks = 0; ks < 2; ++ks)
                    af[mi][ks] = *(const short8*)&Ab[buf][wr]
                        [((p * 2 + mi) * 16 + l15) * 64 +
                         (((ks << 2) + lhi) ^ rsw) * 8];
            // staged prefetch (1 half-tile per phase)
            if (p == 0 && u + 1 < NT) stageA(buf ^ 1, 0, (u + 1) << 6);
            if (p == 1 && u + 1 < NT) stageA(buf ^ 1, 1, (u + 1) << 6);
            if (p == 2 && u + 2 < NT) stageB(buf, 0, (u + 2) << 6);
            if (p == 3 && u + 2 < NT) stageB(buf, 1, (u + 2) << 6);
            __builtin_amdgcn_s_barrier();          // entry
            __builtin_amdgcn_s_setprio(1);
#pragma unroll
            for (int mi = 0; mi < 2; ++mi)
#pragma unroll
                for (int n = 0; n < 4; ++n)
#pragma unroll
                    for (int ks = 0; ks < 2; ++ks)
                        acc[p * 2 + mi][n] = __builtin_amdgcn_mfma_f32_16x16x32_bf16(
                            af[mi][ks], bfr[n][ks], acc[p * 2 + mi][n], 0, 0, 0);
            __builtin_amdgcn_s_setprio(0);
            if (p == 3 && u + 1 < NT) {
                // tile u+1 must be landed after the next barrier
                if (u + 2 < NT) asm volatile("s_waitcnt vmcnt(4)" ::: "memory");
                else            asm volatile("s_waitcnt vmcnt(0)" ::: "memory");
            }
            __builtin_amdgcn_s_barrier();          // closing / publication
        }
    }

#pragma unroll
    for (int m = 0; m < 8; ++m)
#pragma unroll
        for (int n = 0; n < 4; ++n)
#pragma unroll
            for (int r = 0; r < 4; ++r) {
                int row = row0 + wr * 128 + m * 16 + lhi * 4 + r;
                int col = col0 + wc * 64 + n * 16 + l15;
                float v = acc[m][n][r];
                if (HAS_BIAS) v += bias[col];
                if (RELU) v = fmaxf(v, 0.f);
                out[(size_t)row * N + col] = f2bf(v);
            }
}

// ---------------- bf16 GEMM 128xBN (kept for N=1024 shapes): PIPE=1 counted vmcnt ----------------
template <int BN, int PIPE, bool HAS_BIAS, bool RELU, bool RESID, bool OUT_BF16>
__global__ __launch_bounds__(256) void gemm_bt(const short* __restrict__ A,
                                               const short* __restrict__ Bt,
                                               const float* __restrict__ bias,
                                               const float* __restrict__ resid,
                                               void* __restrict__ outp,
                                               int M, int N, int K) {
    constexpr int WRC = (BN == 128) ? 2 : 4;
    constexpr int WCC = (BN == 128) ? 2 : 1;
    constexpr int MI = 8 / WRC;
    constexpr int NI = BN / (16 * WCC);
    constexpr int BCH = BN / 32;
    constexpr int ASZ = 128 * 64, BSZ = BN * 64;

    __shared__ __align__(16) short As[(PIPE ? 2 : 1) * ASZ];
    __shared__ __align__(16) short Bs[(PIPE ? 2 : 1) * BSZ];

    const int tid = threadIdx.x;
    const int lane = tid & 63;
    const int wid = tid >> 6;
    const int wr = (WRC == 2) ? (wid >> 1) : wid;
    const int wc = (WCC == 2) ? (wid & 1) : 0;
    const int l15 = lane & 15, lhi = lane >> 4;

    int wg = blockIdx.y * gridDim.x + blockIdx.x;
    const int chunk = (gridDim.x * gridDim.y) >> 3;
    wg = (wg & 7) * chunk + (wg >> 3);
    const int bx = wg % gridDim.x;
    const int by = wg / gridDim.x;
    const int row0 = by * 128, col0 = bx * BN;

    const int srow = tid >> 3;
    const int scol = (((tid & 7) ^ (srow & 7)) << 3);
    const int rsw = l15 & 7;

    const int wrow0 = wr * (16 * MI);
    const int wcol0 = wc * (16 * NI);

    f32x4 acc[MI][NI] = {};

    auto stage = [&](int k0, int bs) {   // 4 + BCH = 6 vmem insts/wave (BN=64)
#pragma unroll
        for (int ch = 0; ch < 4; ++ch)
            gld16(&A[(size_t)(row0 + ch * 32 + srow) * K + k0 + scol],
                  &As[bs * ASZ + ch * 2048 + wid * 512]);
#pragma unroll
        for (int ch = 0; ch < BCH; ++ch)
            gld16(&Bt[(size_t)(col0 + ch * 32 + srow) * K + k0 + scol],
                  &Bs[bs * BSZ + ch * 2048 + wid * 512]);
    };
    auto compute = [&](int bs) {
#pragma unroll
        for (int ks = 0; ks < 2; ++ks) {
            short8 af[MI], bf[NI];
#pragma unroll
            for (int mi = 0; mi < MI; ++mi)
                af[mi] = *(const short8*)&As[bs * ASZ + (wrow0 + mi * 16 + l15) * 64 +
                                             (((ks << 2) + lhi) ^ rsw) * 8];
#pragma unroll
            for (int ni = 0; ni < NI; ++ni)
                bf[ni] = *(const short8*)&Bs[bs * BSZ + (wcol0 + ni * 16 + l15) * 64 +
                                             (((ks << 2) + lhi) ^ rsw) * 8];
#pragma unroll
            for (int mi = 0; mi < MI; ++mi)
#pragma unroll
                for (int ni = 0; ni < NI; ++ni)
                    acc[mi][ni] = __builtin_amdgcn_mfma_f32_16x16x32_bf16(
                        af[mi], bf[ni], acc[mi][ni], 0, 0, 0);
        }
    };

    if (PIPE == 1) {
        const int nt = K >> 6;
        stage(0, 0);
        stage(64, 1);
        int cur = 0;
        for (int t = 0; t < nt; ++t) {
            if (t + 1 < nt) asm volatile("s_waitcnt vmcnt(6)" ::: "memory");
            else            asm volatile("s_waitcnt vmcnt(0)" ::: "memory");
            __builtin_amdgcn_s_barrier();
            __builtin_amdgcn_sched_barrier(0);
            compute(cur);
            __builtin_amdgcn_sched_barrier(0);
            __builtin_amdgcn_s_barrier();
            if (t + 2 < nt) stage((t + 2) << 6, cur);
            cur ^= 1;
        }
    } else {
        for (int k0 = 0; k0 < K; k0 += 64) {
            __syncthreads();
            stage(k0, 0);
            __syncthreads();
            compute(0);
        }
    }

    float* outf = (float*)outp;
    short* outb = (short*)outp;
#pragma unroll
    for (int mi = 0; mi < MI; ++mi)
#pragma unroll
        for (int ni = 0; ni < NI; ++ni)
#pragma unroll
            for (int r = 0; r < 4; ++r) {
                int row = row0 + wrow0 + mi * 16 + lhi * 4 + r;
                int col = col0 + wcol0 + ni * 16 + l15;
                float v = acc[mi][ni][r];
                if (HAS_BIAS) v += bias[col];
                if (RELU) v = fmaxf(v, 0.f);
                if (RESID) v += resid[(size_t)row * N + col];
                if (OUT_BF16) outb[(size_t)row * N + col] = f2bf(v);
                else outf[(size_t)row * N + col] = v;
            }
}

// ---------------- flash attention: swapped QK^T, in-lane softmax (T12-style) ----------------
__global__ __launch_bounds__(256) void attn_kernel(const short* __restrict__ qkv,
                                                   const short* __restrict__ vT,
                                                   short* __restrict__ obuf) {
    __shared__ __align__(16) short Ks[2][64 * 64];
    __shared__ __align__(16) short Vs[2][64 * 64];
    __shared__ __align__(16) unsigned int Pl[4][2][16][40];
    const int tid = threadIdx.x;
    const int lane = tid & 63;
    const int wid = tid >> 6;
    const int l15 = lane & 15, lhi = lane >> 4;
    const int lhi4 = lhi * 4;

    const int nb = ((blockIdx.x & 7) << 6) + (blockIdx.x >> 3);
    const int b = nb >> 7;
    const int h = (nb >> 3) & 15;
    const int q0 = (nb & 7) << 7;
    const size_t rbase = (size_t)b * TT;
    const int hq = h * 64;
    const short* vg = vT + ((size_t)b * 1024 + hq) * TT;

    const int srow = tid >> 3;
    const int scol = (((tid & 7) ^ (srow & 7)) << 3);
    const int rsw = (l15 & 7);

    short8 aq[2][2];
#pragma unroll
    for (int g = 0; g < 2; ++g)
#pragma unroll
        for (int ks = 0; ks < 2; ++ks)
            aq[g][ks] = *(const short8*)&qkv[(rbase + q0 + wid * 32 + g * 16 + l15) * NQKV +
                                             hq + ks * 32 + lhi * 8];

    float mrun[2] = {-INFINITY, -INFINITY};
    float lsum[2] = {0.f, 0.f};
    f32x4 o[2][4] = {};

#pragma unroll
    for (int ch = 0; ch < 2; ++ch) {
        gld16(&qkv[(rbase + 0 + ch * 32 + srow) * NQKV + 1024 + hq + scol],
              &Ks[0][ch * 2048 + wid * 512]);
        gld16(&vg[(size_t)(ch * 32 + srow) * TT + 0 + scol],
              &Vs[0][ch * 2048 + wid * 512]);
    }
    __syncthreads();

    int cur = 0;
    for (int st = 0; st < TT; st += 64) {
        if (st + 64 < TT) {
#pragma unroll
            for (int ch = 0; ch < 2; ++ch) {
                gld16(&qkv[(rbase + st + 64 + ch * 32 + srow) * NQKV + 1024 + hq + scol],
                      &Ks[cur ^ 1][ch * 2048 + wid * 512]);
                gld16(&vg[(size_t)(ch * 32 + srow) * TT + st + 64 + scol],
                      &Vs[cur ^ 1][ch * 2048 + wid * 512]);
            }
        }
        const short* K = &Ks[cur][0];
        const short* V = &Vs[cur][0];

        short8 kf[4][2];
#pragma unroll
        for (int nt = 0; nt < 4; ++nt)
#pragma unroll
            for (int ks = 0; ks < 2; ++ks)
                kf[nt][ks] = *(const short8*)&K[(nt * 16 + l15) * 64 +
                                               (((ks << 2) + lhi) ^ rsw) * 8];

        short8 pa[2][2];
#pragma unroll
        for (int g = 0; g < 2; ++g) {
            f32x4 stv[4] = {};
#pragma unroll
            for (int nt = 0; nt < 4; ++nt)
#pragma unroll
                for (int ks = 0; ks < 2; ++ks)
                    stv[nt] = __builtin_amdgcn_mfma_f32_16x16x32_bf16(
                        kf[nt][ks], aq[g][ks], stv[nt], 0, 0, 0);
            float tn[4];
#pragma unroll
            for (int nt = 0; nt < 4; ++nt)
                tn[nt] = fmaxf(fmaxf(stv[nt][0], stv[nt][1]),
                               fmaxf(stv[nt][2], stv[nt][3]));
            float tm = fmaxf(fmaxf(tn[0], tn[1]), fmaxf(tn[2], tn[3]));
            tm = fmaxf(tm, __shfl_xor(tm, 16, 64));
            tm = fmaxf(tm, __shfl_xor(tm, 32, 64));
            const bool full = !__all(tm - mrun[g] <= 11.5f);
            if (full) {
                float mnew = fmaxf(mrun[g], tm);
                float fac = exp2f(mrun[g] - mnew);
                mrun[g] = mnew;
                lsum[g] *= fac;
                float f0 = __shfl(fac, lhi4 + 0, 64);
                float f1 = __shfl(fac, lhi4 + 1, 64);
                float f2 = __shfl(fac, lhi4 + 2, 64);
                float f3 = __shfl(fac, lhi4 + 3, 64);
#pragma unroll
                for (int dt = 0; dt < 4; ++dt) {
                    o[g][dt][0] *= f0; o[g][dt][1] *= f1;
                    o[g][dt][2] *= f2; o[g][dt][3] *= f3;
                }
            }
            float pv[4][4];
            float sn[4];
#pragma unroll
            for (int nt = 0; nt < 4; ++nt) {
#pragma unroll
                for (int r = 0; r < 4; ++r) pv[nt][r] = exp2f(stv[nt][r] - mrun[g]);
                sn[nt] = (pv[nt][0] + pv[nt][1]) + (pv[nt][2] + pv[nt][3]);
            }
            float rs = (sn[0] + sn[1]) + (sn[2] + sn[3]);
            rs += __shfl_xor(rs, 16, 64);
            rs += __shfl_xor(rs, 32, 64);
            lsum[g] += rs;
#pragma unroll
            for (int nt = 0; nt < 4; ++nt) {
                uint2 ww;
                ww.x = cvtpk_bf16(pv[nt][0], pv[nt][1]);
                ww.y = cvtpk_bf16(pv[nt][2], pv[nt][3]);
                *(uint2*)&Pl[wid][g][l15][nt * 8 + lhi * 2] = ww;
            }
            pa[g][0] = *(const short8*)&Pl[wid][g][l15][lhi4];
            pa[g][1] = *(const short8*)&Pl[wid][g][l15][16 + lhi4];
        }

        short8 vf[4][2];
#pragma unroll
        for (int dt = 0; dt < 4; ++dt)
#pragma unroll
            for (int k2 = 0; k2 < 2; ++k2)
                vf[dt][k2] = *(const short8*)&V[(dt * 16 + l15) * 64 +
                                               (((k2 << 2) + lhi) ^ rsw) * 8];
#pragma unroll
        for (int g = 0; g < 2; ++g)
#pragma unroll
            for (int dt = 0; dt < 4; ++dt)
#pragma unroll
                for (int k2 = 0; k2 < 2; ++k2)
                    o[g][dt] = __builtin_amdgcn_mfma_f32_16x16x32_bf16(
                        pa[g][k2], vf[dt][k2], o[g][dt], 0, 0, 0);

        __syncthreads();
        cur ^= 1;
    }
#pragma unroll
    for (int g = 0; g < 2; ++g) {
        float inv = 1.0f / lsum[g];
        float i0 = __shfl(inv, lhi4 + 0, 64);
        float i1 = __shfl(inv, lhi4 + 1, 64);
        float i2 = __shfl(inv, lhi4 + 2, 64);
        float i3 = __shfl(inv, lhi4 + 3, 64);
#pragma unroll
        for (int dt = 0; dt < 4; ++dt) {
            int col = hq + dt * 16 + l15;
            size_t rw = rbase + q0 + wid * 32 + g * 16 + lhi4;
            obuf[(rw + 0) * EE + col] = f2bf(o[g][dt][0] * i0);
            obuf[(rw + 1) * EE + col] = f2bf(o[g][dt][1] * i1);
            obuf[(rw + 2) * EE + col] = f2bf(o[g][dt][2] * i2);
            obuf[(rw + 3) * EE + col] = f2bf(o[g][dt][3] * i3);
        }
    }
}

// ---------------- launch ----------------
extern "C" void kernel_launch(void* const* d_in, const int* in_sizes, int n_in,
                              void* d_out, int out_size, void* d_ws, size_t ws_size,
                              hipStream_t stream) {
    const float* x   = (const float*)d_in[0];
    const float* g1  = (const float*)d_in[1];
    const float* be1 = (const float*)d_in[2];
    const float* Wq  = (const float*)d_in[3];
    const float* Wk  = (const float*)d_in[4];
    const float* Wv  = (const float*)d_in[5];
    const float* Wp  = (const float*)d_in[6];
    const float* bp  = (const float*)d_in[7];
    const float* g2  = (const float*)d_in[8];
    const float* be2 = (const float*)d_in[9];
    const float* W1  = (const float*)d_in[10];
    const float* b1f = (const float*)d_in[11];
    const float* W2  = (const float*)d_in[12];
    const float* b2f = (const float*)d_in[13];

    char* p = (char*)d_ws;
    short* h_bf   = (short*)p; p += (size_t)MM * EE * 2;
    short* wqkv   = (short*)p; p += (size_t)EE * NQKV * 2;   // [3072][1024] W^T (K pre-scaled)
    short* qkv    = (short*)p; p += (size_t)MM * NQKV * 2;
    short* o_bf   = (short*)p; p += (size_t)MM * EE * 2;
    short* wp_bf  = (short*)p; p += (size_t)EE * EE * 2;     // [1024][1024] Wp^T
    float* x1     = (float*)p; p += (size_t)MM * EE * 4;
    short* h2_bf  = (short*)p; p += (size_t)MM * EE * 2;
    short* w1_bf  = (short*)p; p += (size_t)EE * E4 * 2;     // [4096][1024] W1^T
    short* mid_bf = (short*)p; p += (size_t)MM * E4 * 2;
    short* w2_bf  = (short*)p; p += (size_t)E4 * EE * 2;     // [1024][4096] W2^T
    short* vTb    = (short*)p; p += (size_t)BB * 1024 * TT * 2;  // [b][h*64+d][t]

    pack_qkv_t<<<dim3(16, 48), 256, 0, stream>>>(Wq, Wk, Wv, wqkv);
    tcvt_kernel<<<dim3(16, 16), 256, 0, stream>>>(Wp, wp_bf, EE, EE);
    tcvt_kernel<<<dim3(64, 16), 256, 0, stream>>>(W1, w1_bf, EE, E4);
    tcvt_kernel<<<dim3(16, 64), 256, 0, stream>>>(W2, w2_bf, E4, EE);

    ln_kernel<<<MM, 256, 0, stream>>>(x, g1, be1, h_bf);

    gemm256<false, false>
        <<<dim3(NQKV / 256, MM / 256), 512, 0, stream>>>(h_bf, wqkv, nullptr,
                                                         qkv, MM, NQKV, EE);

    vtr_kernel<<<dim3(16, 16, BB), 256, 0, stream>>>(qkv, vTb);

    attn_kernel<<<BB * HH * (TT / 128), 256, 0, stream>>>(qkv, vTb, o_bf);

    gemm_bt<64, 1, true, false, true, false>
        <<<dim3(EE / 64, MM / 128), 256, 0, stream>>>(o_bf, wp_bf, bp, x, x1, MM, EE, EE);

    ln_kernel<<<MM, 256, 0, stream>>>(x1, g2, be2, h2_bf);

    gemm256<true, true>
        <<<dim3(E4 / 256, MM / 256), 512, 0, stream>>>(h2_bf, w1_bf, b1f,
                                                       mid_bf, MM, E4, EE);

    gemm_bt<64, 1, true, false, true, false>
        <<<dim3(EE / 64, MM / 128), 256, 0, stream>>>(mid_bf, w2_bf, b2f, x1,
                                                      (float*)d_out, MM, EE, E4);
}